// Round 1
// 493.921 us; speedup vs baseline: 1.0444x; 1.0444x over previous
//
#include <hip/hip_runtime.h>
#include <stdint.h>

#define B_ 2
#define N_ 4096
#define D_ 256
#define H_ 8
#define DH_ 64
#define INNER_ 512
#define NBH 16
#define PAD 72
#define FPAD 80

typedef unsigned short ushort_t;
typedef __attribute__((ext_vector_type(8))) short short8;
typedef __attribute__((ext_vector_type(4))) float float4v;
typedef __attribute__((ext_vector_type(4))) unsigned short ushort4v;
typedef __attribute__((ext_vector_type(4))) unsigned int uint4v;

__device__ __forceinline__ ushort_t f2bf(float f) {
    union { float f; unsigned int u; } v; v.f = f;
    unsigned int r = v.u + 0x7FFFu + ((v.u >> 16) & 1u);
    return (ushort_t)(r >> 16);
}
__device__ __forceinline__ float bf2f(ushort_t u) {
    union { unsigned int u; float f; } v; v.u = ((unsigned int)u) << 16;
    return v.f;
}
// full signed fp8 e4m3 encode with subnormal + clamp handling (for t values)
__device__ __forceinline__ unsigned char f2fp8s(float f) {
    union { float f; unsigned int u; } v; v.f = f;
    unsigned int s = (v.u >> 24) & 0x80u;
    v.u &= 0x7FFFFFFFu;
    float a = v.f;
    if (a >= 448.f) return (unsigned char)(s | 0x7E);
    if (a < 0.015625f) {
        int m = (int)(a * 512.f + 0.5f);
        return (unsigned char)(s | (unsigned)m);
    }
    unsigned int u = v.u + 0x7FFFFu + ((v.u >> 20) & 1u);
    return (unsigned char)(s | (((u >> 20) & 0x7FF) - 960));
}

// ---------------- prep: bf16 conversions + weight transposes ----------------
__global__ __launch_bounds__(256) void prep_kernel(
    const float* __restrict__ x, const float* __restrict__ Wq,
    const float* __restrict__ Wk, const float* __restrict__ Wv,
    const float* __restrict__ Wo,
    ushort_t* __restrict__ xb, ushort_t* __restrict__ WqkvT,
    ushort_t* __restrict__ WoT) {
    int idx = blockIdx.x * 256 + threadIdx.x;
    const int total_x = B_ * N_ * D_;
    const int total_wqkv = 3 * INNER_ * D_;
    const int total_wo = D_ * INNER_;
    if (idx < total_x) { xb[idx] = f2bf(x[idx]); return; }
    idx -= total_x;
    if (idx < total_wqkv) {
        int n = idx >> 8, k = idx & 255;
        int which = n >> 9, nn = n & 511;
        const float* W = (which == 0) ? Wq : ((which == 1) ? Wk : Wv);
        WqkvT[idx] = f2bf(W[k * INNER_ + nn]);
        return;
    }
    idx -= total_wqkv;
    if (idx < total_wo) {
        int c = idx >> 9, k = idx & 511;
        WoT[idx] = f2bf(Wo[k * D_ + c]);
    }
}

// ---------------- fused QKV projection GEMM: [8192,256] x [256,1536] --------
__global__ __launch_bounds__(256) void proj_gemm(
    const ushort_t* __restrict__ xb, const ushort_t* __restrict__ WqkvT,
    ushort_t* __restrict__ Qb, ushort_t* __restrict__ Kb,
    ushort_t* __restrict__ Vb) {
    __shared__ ushort_t As[128][PAD];
    __shared__ ushort_t Bs[128][PAD];
    int bid = blockIdx.x;
    int tileN = bid % 12, tileM = bid / 12;
    int tid = threadIdx.x;
    int w = tid >> 6, lane = tid & 63, q = lane >> 4, r = lane & 15;
    int wr = (w & 1) * 64, wc = (w >> 1) * 64;
    float4v acc[4][4];
    for (int i = 0; i < 4; i++)
        for (int j = 0; j < 4; j++)
            for (int e = 0; e < 4; e++) acc[i][j][e] = 0.f;

    for (int k0 = 0; k0 < 256; k0 += 64) {
        for (int it = 0; it < 4; it++) {
            int idx = tid + it * 256;
            int row = idx >> 3, kc = (idx & 7) * 8;
            *(short8*)&As[row][kc] =
                *(const short8*)&xb[(size_t)(tileM * 128 + row) * 256 + k0 + kc];
            *(short8*)&Bs[row][kc] =
                *(const short8*)&WqkvT[(size_t)(tileN * 128 + row) * 256 + k0 + kc];
        }
        __syncthreads();
        for (int kk = 0; kk < 64; kk += 32) {
            short8 a[4], b[4];
            for (int mi = 0; mi < 4; mi++)
                a[mi] = *(const short8*)&As[wr + mi * 16 + r][kk + q * 8];
            for (int ni = 0; ni < 4; ni++)
                b[ni] = *(const short8*)&Bs[wc + ni * 16 + r][kk + q * 8];
            for (int mi = 0; mi < 4; mi++)
                for (int ni = 0; ni < 4; ni++)
                    acc[mi][ni] = __builtin_amdgcn_mfma_f32_16x16x32_bf16(
                        a[mi], b[ni], acc[mi][ni], 0, 0, 0);
        }
        __syncthreads();
    }
    for (int mi = 0; mi < 4; mi++)
        for (int ni = 0; ni < 4; ni++)
            for (int reg = 0; reg < 4; reg++) {
                int grow = tileM * 128 + wr + mi * 16 + q * 4 + reg;
                int gcol = tileN * 128 + wc + ni * 16 + r;
                float v = acc[mi][ni][reg];
                int which = gcol >> 9, inner = gcol & 511;
                int h = inner >> 6, d = inner & 63;
                int b = grow >> 12, n = grow & 4095;
                size_t off = (((size_t)(b * H_ + h)) * N_ + n) * DH_ + d;
                if (which == 0) Qb[off] = f2bf(v);
                else if (which == 1) Kb[off] = f2bf(v);
                else Vb[off] = f2bf(v);
            }
}

// ---------------- per-head LayerNorm + y init + transposed fp8 t0 -----------
__global__ __launch_bounds__(256) void ln_kernel(
    const ushort_t* __restrict__ Vb, const float* __restrict__ gamma,
    const float* __restrict__ beta, const float* __restrict__ coeffs,
    unsigned char* __restrict__ t0T, float* __restrict__ y) {
    int tid = threadIdx.x;
    int wave = tid >> 6, lane = tid & 63;
    size_t row = (size_t)blockIdx.x * 4 + wave;   // bh*4096 + n
    int bh = (int)(row >> 12), n = (int)(row & 4095);
    int h = bh & 7;
    float v = bf2f(Vb[row * 64 + lane]);
    float s = v;
    for (int m = 32; m >= 1; m >>= 1) s += __shfl_xor(s, m, 64);
    float mu = s * (1.f / 64.f);
    float dv = v - mu;
    float s2 = dv * dv;
    for (int m = 32; m >= 1; m >>= 1) s2 += __shfl_xor(s2, m, 64);
    float var = s2 * (1.f / 64.f);
    float vln = dv * rsqrtf(var + 1e-5f) * gamma[lane] + beta[lane];
    float c0 = coeffs[h * 4 + 0];
    y[row * 64 + lane] = c0 * vln;
    t0T[((size_t)bh * 64 + lane) * 4096 + n] = f2fp8s(vln);
}

// ---------------- E = exp(Q K^T / 8), fp8, coalesced dwordx4 stores ---------
// Swapped MFMA operands (A=K, B=Q) so per-lane regs run along j (E columns):
// pack 4 fp8 via v_cvt_pk_fp8_f32, bounce through LDS, store dwordx4.
__global__ __launch_bounds__(256) void s_kernel(
    const ushort_t* __restrict__ Qb, const ushort_t* __restrict__ Kb,
    unsigned char* __restrict__ E, int bh0) {
    __shared__ char smem[36864];
    ushort_t (*As)[PAD] = (ushort_t(*)[PAD])smem;            // Q tile 128x64
    ushort_t (*Bs)[PAD] = (ushort_t(*)[PAD])(smem + 18432);  // K tile 128x64
    unsigned int* E8 = (unsigned int*)smem;                   // 128 x 36 uints
    int bid = blockIdx.x;
    int local = bid >> 10;
    int rem = bid & 1023;
    int ti = rem >> 5, tj = rem & 31;
    int bh = bh0 + local;
    const ushort_t* Q = Qb + (size_t)bh * N_ * 64;
    const ushort_t* K = Kb + (size_t)bh * N_ * 64;
    unsigned char* Eg = E + (size_t)local * N_ * N_;
    int tid = threadIdx.x, w = tid >> 6, lane = tid & 63, q = lane >> 4, r = lane & 15;
    int wj = (w & 1) * 64, wi = (w >> 1) * 64;
    float4v acc[4][4];
    for (int i = 0; i < 4; i++)
        for (int j = 0; j < 4; j++)
            for (int e = 0; e < 4; e++) acc[i][j][e] = 0.f;

    for (int it = 0; it < 4; it++) {
        int idx = tid + it * 256;
        int row = idx >> 3, kc = (idx & 7) * 8;
        *(short8*)&As[row][kc] = *(const short8*)&Q[(size_t)(ti * 128 + row) * 64 + kc];
        *(short8*)&Bs[row][kc] = *(const short8*)&K[(size_t)(tj * 128 + row) * 64 + kc];
    }
    __syncthreads();
    for (int kk = 0; kk < 64; kk += 32) {
        short8 a[4], b[4];
        for (int mi = 0; mi < 4; mi++)             // A = K rows (j direction)
            a[mi] = *(const short8*)&Bs[wj + mi * 16 + r][kk + q * 8];
        for (int ni = 0; ni < 4; ni++)             // B = Q rows (i direction)
            b[ni] = *(const short8*)&As[wi + ni * 16 + r][kk + q * 8];
        for (int mi = 0; mi < 4; mi++)
            for (int ni = 0; ni < 4; ni++)
                acc[mi][ni] = __builtin_amdgcn_mfma_f32_16x16x32_bf16(
                    a[mi], b[ni], acc[mi][ni], 0, 0, 0);
    }
    __syncthreads();   // done with As/Bs; reuse as E8
    for (int mi = 0; mi < 4; mi++)
        for (int ni = 0; ni < 4; ni++) {
            float f0 = __expf(0.125f * acc[mi][ni][0]);
            float f1 = __expf(0.125f * acc[mi][ni][1]);
            float f2 = __expf(0.125f * acc[mi][ni][2]);
            float f3 = __expf(0.125f * acc[mi][ni][3]);
            int p = __builtin_amdgcn_cvt_pk_fp8_f32(f0, f1, 0, false);
            p = __builtin_amdgcn_cvt_pk_fp8_f32(f2, f3, p, true);
            int il = wi + ni * 16 + r;                       // E row i (local)
            int j4 = ((wj + mi * 16) >> 2) + q;              // E col / 4
            E8[il * 36 + j4] = (unsigned int)p;
        }
    __syncthreads();
    for (int it = 0; it < 4; it++) {
        int idx = tid + it * 256;                  // 0..1023
        int row = idx >> 3, c4 = (idx & 7) * 4;
        uint4v vv = *(const uint4v*)&E8[row * 36 + c4];
        *(uint4v*)&Eg[(size_t)(ti * 128 + row) * 4096 + tj * 128 + c4 * 4] = vv;
    }
}

// ---------------- fused polynomial filter pass + normalize + y update -------
// One block = 64 output rows over the FULL k=4096 range (SPLIT removed).
// E operand feeds MFMA straight from VGPRs (no LDS staging: each wave reads a
// disjoint 16-row slice of E -> zero cross-wave reuse, LDS was pure overhead).
// t tile (shared by all 4 waves) is double-buffered in LDS with a single raw
// s_barrier per 64-j chunk; global prefetches are issued 2 half-chunks ahead
// and SURVIVE the barrier (no __syncthreads vmcnt(0) drain) -> counted vmcnt.
// Epilogue normalizes (t = u / rowsum), does y += ck*t, and emits fp8 t^T.

#define FMFMA(TsX, a0v, a1v)                                                    \
    {                                                                           \
        long b0 = *(const long*)&TsX[r][q * 8];                                 \
        long b1 = *(const long*)&TsX[16 + r][q * 8];                            \
        long b2 = *(const long*)&TsX[32 + r][q * 8];                            \
        long b3 = *(const long*)&TsX[48 + r][q * 8];                            \
        acc[0] = __builtin_amdgcn_mfma_f32_16x16x32_fp8_fp8(a0v, b0, acc[0], 0, 0, 0); \
        acc[1] = __builtin_amdgcn_mfma_f32_16x16x32_fp8_fp8(a0v, b1, acc[1], 0, 0, 0); \
        acc[2] = __builtin_amdgcn_mfma_f32_16x16x32_fp8_fp8(a0v, b2, acc[2], 0, 0, 0); \
        acc[3] = __builtin_amdgcn_mfma_f32_16x16x32_fp8_fp8(a0v, b3, acc[3], 0, 0, 0); \
        accs   = __builtin_amdgcn_mfma_f32_16x16x32_fp8_fp8(a0v, bones, accs, 0, 0, 0); \
        long c0 = *(const long*)&TsX[r][32 + q * 8];                            \
        long c1 = *(const long*)&TsX[16 + r][32 + q * 8];                       \
        long c2 = *(const long*)&TsX[32 + r][32 + q * 8];                       \
        long c3 = *(const long*)&TsX[48 + r][32 + q * 8];                       \
        acc[0] = __builtin_amdgcn_mfma_f32_16x16x32_fp8_fp8(a1v, c0, acc[0], 0, 0, 0); \
        acc[1] = __builtin_amdgcn_mfma_f32_16x16x32_fp8_fp8(a1v, c1, acc[1], 0, 0, 0); \
        acc[2] = __builtin_amdgcn_mfma_f32_16x16x32_fp8_fp8(a1v, c2, acc[2], 0, 0, 0); \
        acc[3] = __builtin_amdgcn_mfma_f32_16x16x32_fp8_fp8(a1v, c3, acc[3], 0, 0, 0); \
        accs   = __builtin_amdgcn_mfma_f32_16x16x32_fp8_fp8(a1v, bones, accs, 0, 0, 0); \
    }

// raw workgroup barrier WITHOUT vmcnt drain: my ds ops are retired
// (lgkmcnt(0)) but global prefetches stay in flight across the barrier.
#define WGBAR()                                                \
    do {                                                       \
        asm volatile("s_waitcnt lgkmcnt(0)" ::: "memory");     \
        __builtin_amdgcn_sched_barrier(0);                     \
        __builtin_amdgcn_s_barrier();                          \
        __builtin_amdgcn_sched_barrier(0);                     \
    } while (0)

__global__ __launch_bounds__(256) void filter_fused(
    const unsigned char* __restrict__ E, const unsigned char* __restrict__ tinT,
    float* __restrict__ y, unsigned char* __restrict__ toutT,
    const float* __restrict__ coeffs, int bh0, int kidx, int write_t) {
    __shared__ unsigned char Ts0[64][FPAD];
    __shared__ unsigned char Ts1[64][FPAD];
    int bid = blockIdx.x;
    int local = bid >> 6;               // bh within resident group
    int ti = bid & 63;                  // 64-row tile index
    int bh = bh0 + local;
    const unsigned char* Eg = E + (size_t)local * N_ * N_;
    const unsigned char* tin = tinT + (size_t)bh * 64 * N_;
    int tid = threadIdx.x, w = tid >> 6, lane = tid & 63, q = lane >> 4, r = lane & 15;

    float4v acc[4], accs;
    for (int e = 0; e < 4; e++) accs[e] = 0.f;
    for (int j = 0; j < 4; j++)
        for (int e = 0; e < 4; e++) acc[j][e] = 0.f;
    const long bones = 0x3838383838383838L;  // 8x fp8(1.0)

    // t staging map: thread -> 16B of the 64x64 chunk (row d, 16 j bytes)
    int srow = tid >> 2, scol = (tid & 3) * 16;
    const unsigned char* tp = tin + (size_t)srow * 4096 + scol;
    // per-lane E pointer for this lane's MFMA A-fragment row
    const unsigned char* ep = Eg + (size_t)(ti * 64 + w * 16 + r) * 4096 + q * 8;

    // prologue: chunk0 staged, t 2 chunks ahead in regs, E 2 chunks in regs
    *(uint4v*)&Ts0[srow][scol] = *(const uint4v*)tp;        // t[0]
    uint4v t_pend_a = *(const uint4v*)(tp + 64);            // t[1]
    uint4v t_pend_b = *(const uint4v*)(tp + 128);           // t[2]
    long eA  = *(const long*)(ep);                          // E[0] lo
    long eB  = *(const long*)(ep + 32);                     // E[0] hi
    long eAn = *(const long*)(ep + 64);                     // E[1] lo
    long eBn = *(const long*)(ep + 96);                     // E[1] hi
    WGBAR();

    for (int it = 0; it < 64; it += 2) {
        // ---- chunk it: read Ts0 (=t[it]); stage Ts1 <- t[it+1]
        *(uint4v*)&Ts1[srow][scol] = t_pend_a;
        t_pend_a = t_pend_b;
        if (it + 3 < 64) t_pend_b = *(const uint4v*)(tp + (size_t)(it + 3) * 64);
        long eA2 = 0, eB2 = 0;
        if (it + 2 < 64) {
            eA2 = *(const long*)(ep + (size_t)(it + 2) * 64);
            eB2 = *(const long*)(ep + (size_t)(it + 2) * 64 + 32);
        }
        FMFMA(Ts0, eA, eB);
        WGBAR();
        // ---- chunk it+1: read Ts1 (=t[it+1]); stage Ts0 <- t[it+2]
        *(uint4v*)&Ts0[srow][scol] = t_pend_a;
        t_pend_a = t_pend_b;
        if (it + 4 < 64) t_pend_b = *(const uint4v*)(tp + (size_t)(it + 4) * 64);
        long eA3 = 0, eB3 = 0;
        if (it + 3 < 64) {
            eA3 = *(const long*)(ep + (size_t)(it + 3) * 64);
            eB3 = *(const long*)(ep + (size_t)(it + 3) * 64 + 32);
        }
        FMFMA(Ts1, eAn, eBn);
        WGBAR();
        eA = eA2; eB = eB2; eAn = eA3; eBn = eB3;
    }

    // ---- epilogue: normalize, y += ck*t, fp8 t^T via LDS bounce ----
    int h = bh & 7;
    float ck = coeffs[h * 4 + kidx];
    float rinv[4];
#pragma unroll
    for (int reg = 0; reg < 4; reg++) rinv[reg] = 1.f / accs[reg];
    float tv[4][4];
#pragma unroll
    for (int ni = 0; ni < 4; ni++)
#pragma unroll
        for (int reg = 0; reg < 4; reg++)
            tv[ni][reg] = acc[ni][reg] * rinv[reg];
#pragma unroll
    for (int reg = 0; reg < 4; reg++) {
        int il = w * 16 + q * 4 + reg;
        float* yp = y + ((size_t)bh * N_ + (size_t)ti * 64 + il) * 64;
#pragma unroll
        for (int ni = 0; ni < 4; ni++)
            yp[ni * 16 + r] += ck * tv[ni][reg];
    }
    if (write_t) {
        // all waves are past the loop's final barrier -> safe to reuse Ts0
        unsigned char (*TT)[FPAD] = Ts0;   // TT[d][n_local], stride 80 (16B-aligned)
#pragma unroll
        for (int ni = 0; ni < 4; ni++) {
            int p = __builtin_amdgcn_cvt_pk_fp8_f32(tv[ni][0], tv[ni][1], 0, false);
            p = __builtin_amdgcn_cvt_pk_fp8_f32(tv[ni][2], tv[ni][3], p, true);
            *(unsigned int*)&TT[ni * 16 + r][w * 16 + q * 4] = (unsigned int)p;
        }
        WGBAR();
        int drow = tid >> 2, dcol = (tid & 3) * 16;
        uint4v vv = *(const uint4v*)&TT[drow][dcol];
        *(uint4v*)&toutT[(size_t)bh * 64 * N_ + (size_t)drow * N_ + ti * 64 + dcol] = vv;
    }
}

// ---------------- output projection: merged[8192,512] x Wo[512,256] ---------
__global__ __launch_bounds__(256) void out_gemm(
    const float* __restrict__ y, const ushort_t* __restrict__ WoT,
    float* __restrict__ out) {
    __shared__ ushort_t As[128][PAD];
    __shared__ ushort_t Bs[64][PAD];
    int bid = blockIdx.x;
    int tileN = bid & 3, tileM = bid >> 2;
    int tid = threadIdx.x, w = tid >> 6, lane = tid & 63, q = lane >> 4, r = lane & 15;
    int wr = w * 32;
    float4v acc[2][4];
    for (int i = 0; i < 2; i++)
        for (int j = 0; j < 4; j++)
            for (int e = 0; e < 4; e++) acc[i][j][e] = 0.f;

    for (int k0 = 0; k0 < 512; k0 += 64) {
        int h = k0 >> 6;
        for (int it = 0; it < 8; it++) {
            int idx = tid + it * 256;
            int row = idx >> 4, kc = (idx & 15) * 4;
            int grow = tileM * 128 + row;
            int b = grow >> 12, n = grow & 4095;
            const float4* src =
                (const float4*)&y[(((size_t)(b * H_ + h)) * N_ + n) * 64 + kc];
            float4 v = *src;
            ushort4v pv;
            pv[0] = f2bf(v.x); pv[1] = f2bf(v.y); pv[2] = f2bf(v.z); pv[3] = f2bf(v.w);
            *(ushort4v*)&As[row][kc] = pv;
        }
        for (int it = 0; it < 2; it++) {
            int idx = tid + it * 256;
            int row = idx >> 3, kc = (idx & 7) * 8;
            *(short8*)&Bs[row][kc] =
                *(const short8*)&WoT[(size_t)(tileN * 64 + row) * 512 + k0 + kc];
        }
        __syncthreads();
        for (int kk = 0; kk < 64; kk += 32) {
            short8 a[2], b[4];
            a[0] = *(const short8*)&As[wr + r][kk + q * 8];
            a[1] = *(const short8*)&As[wr + 16 + r][kk + q * 8];
            for (int ni = 0; ni < 4; ni++)
                b[ni] = *(const short8*)&Bs[ni * 16 + r][kk + q * 8];
            for (int mi = 0; mi < 2; mi++)
                for (int ni = 0; ni < 4; ni++)
                    acc[mi][ni] = __builtin_amdgcn_mfma_f32_16x16x32_bf16(
                        a[mi], b[ni], acc[mi][ni], 0, 0, 0);
        }
        __syncthreads();
    }
    for (int mi = 0; mi < 2; mi++)
        for (int reg = 0; reg < 4; reg++) {
            int grow = tileM * 128 + wr + mi * 16 + q * 4 + reg;
            for (int ni = 0; ni < 4; ni++) {
                int gcol = tileN * 64 + ni * 16 + r;
                out[(size_t)grow * 256 + gcol] = acc[mi][ni][reg];
            }
        }
}

// ---------------------------------------------------------------------------
extern "C" void kernel_launch(void* const* d_in, const int* in_sizes, int n_in,
                              void* d_out, int out_size, void* d_ws, size_t ws_size,
                              hipStream_t stream) {
    const float* x      = (const float*)d_in[0];
    const float* Wq     = (const float*)d_in[1];
    const float* Wk     = (const float*)d_in[2];
    const float* Wv     = (const float*)d_in[3];
    const float* Wo     = (const float*)d_in[4];
    const float* gamma  = (const float*)d_in[5];
    const float* beta   = (const float*)d_in[6];
    const float* coeffs = (const float*)d_in[7];
    float* out = (float*)d_out;

    char* ws = (char*)d_ws;
    size_t off = 0;
    auto alloc = [&](size_t bytes) -> void* {
        void* p = ws + off;
        off += (bytes + 255) & ~(size_t)255;
        return p;
    };
    ushort_t* xb    = (ushort_t*)alloc((size_t)B_ * N_ * D_ * 2);
    ushort_t* WqkvT = (ushort_t*)alloc((size_t)3 * INNER_ * D_ * 2);
    ushort_t* WoT   = (ushort_t*)alloc((size_t)D_ * INNER_ * 2);
    ushort_t* Qb    = (ushort_t*)alloc((size_t)NBH * N_ * DH_ * 2);
    ushort_t* Kb    = (ushort_t*)alloc((size_t)NBH * N_ * DH_ * 2);
    unsigned char* t0T = (unsigned char*)alloc((size_t)NBH * DH_ * N_);
    unsigned char* t1T = (unsigned char*)alloc((size_t)NBH * DH_ * N_);
    float*    y     = (float*)alloc((size_t)NBH * N_ * DH_ * 4);

    const size_t E1 = (size_t)N_ * N_;  // 16.78 MB per (b,h) in fp8
    int nbh_g = 8;
    while (nbh_g > 1) {
        size_t need = off + (size_t)nbh_g * E1;
        if (need <= ws_size) break;
        nbh_g >>= 1;
    }
    unsigned char* E = (unsigned char*)(ws + off);
    // V (bf16, 8.4 MB) aliased onto the E region: dead once ln_kernel has run,
    // before the first s_kernel write.
    ushort_t* Vb = (ushort_t*)E;

    const int prep_total = B_ * N_ * D_ + 3 * INNER_ * D_ + D_ * INNER_;
    prep_kernel<<<(prep_total + 255) / 256, 256, 0, stream>>>(
        x, Wq, Wk, Wv, Wo, xb, WqkvT, WoT);
    proj_gemm<<<768, 256, 0, stream>>>(xb, WqkvT, Qb, Kb, Vb);
    ln_kernel<<<(NBH * N_) / 4, 256, 0, stream>>>(Vb, gamma, beta, coeffs, t0T, y);

    int fgrid = nbh_g * 64;

    for (int bh0 = 0; bh0 < NBH; bh0 += nbh_g) {
        s_kernel<<<nbh_g * 1024, 256, 0, stream>>>(Qb, Kb, E, bh0);
        filter_fused<<<fgrid, 256, 0, stream>>>(E, t0T, y, t1T, coeffs, bh0, 1, 1);
        filter_fused<<<fgrid, 256, 0, stream>>>(E, t1T, y, t0T, coeffs, bh0, 2, 1);
        filter_fused<<<fgrid, 256, 0, stream>>>(E, t0T, y, t1T, coeffs, bh0, 3, 0);
    }
    out_gemm<<<256, 256, 0, stream>>>(y, WoT, out);
}

// Round 2
// 424.166 us; speedup vs baseline: 1.2162x; 1.1645x over previous
//
#include <hip/hip_runtime.h>
#include <stdint.h>

#define B_ 2
#define N_ 4096
#define D_ 256
#define H_ 8
#define DH_ 64
#define INNER_ 512
#define NBH 16
#define PAD 72
#define FPAD 80

typedef unsigned short ushort_t;
typedef __attribute__((ext_vector_type(8))) short short8;
typedef __attribute__((ext_vector_type(4))) float float4v;
typedef __attribute__((ext_vector_type(4))) unsigned short ushort4v;
typedef __attribute__((ext_vector_type(4))) unsigned int uint4v;

__device__ __forceinline__ ushort_t f2bf(float f) {
    union { float f; unsigned int u; } v; v.f = f;
    unsigned int r = v.u + 0x7FFFu + ((v.u >> 16) & 1u);
    return (ushort_t)(r >> 16);
}
__device__ __forceinline__ float bf2f(ushort_t u) {
    union { unsigned int u; float f; } v; v.u = ((unsigned int)u) << 16;
    return v.f;
}
// full signed fp8 e4m3 encode with subnormal + clamp handling (for t values)
__device__ __forceinline__ unsigned char f2fp8s(float f) {
    union { float f; unsigned int u; } v; v.f = f;
    unsigned int s = (v.u >> 24) & 0x80u;
    v.u &= 0x7FFFFFFFu;
    float a = v.f;
    if (a >= 448.f) return (unsigned char)(s | 0x7E);
    if (a < 0.015625f) {
        int m = (int)(a * 512.f + 0.5f);
        return (unsigned char)(s | (unsigned)m);
    }
    unsigned int u = v.u + 0x7FFFFu + ((v.u >> 20) & 1u);
    return (unsigned char)(s | (((u >> 20) & 0x7FF) - 960));
}

// ---------------- prep: bf16 conversions + weight transposes ----------------
__global__ __launch_bounds__(256) void prep_kernel(
    const float* __restrict__ x, const float* __restrict__ Wq,
    const float* __restrict__ Wk, const float* __restrict__ Wv,
    const float* __restrict__ Wo,
    ushort_t* __restrict__ xb, ushort_t* __restrict__ WqkvT,
    ushort_t* __restrict__ WoT) {
    int idx = blockIdx.x * 256 + threadIdx.x;
    const int total_x = B_ * N_ * D_;
    const int total_wqkv = 3 * INNER_ * D_;
    const int total_wo = D_ * INNER_;
    if (idx < total_x) { xb[idx] = f2bf(x[idx]); return; }
    idx -= total_x;
    if (idx < total_wqkv) {
        int n = idx >> 8, k = idx & 255;
        int which = n >> 9, nn = n & 511;
        const float* W = (which == 0) ? Wq : ((which == 1) ? Wk : Wv);
        WqkvT[idx] = f2bf(W[k * INNER_ + nn]);
        return;
    }
    idx -= total_wqkv;
    if (idx < total_wo) {
        int c = idx >> 9, k = idx & 511;
        WoT[idx] = f2bf(Wo[k * D_ + c]);
    }
}

// ---------------- fused QKV projection GEMM: [8192,256] x [256,1536] --------
__global__ __launch_bounds__(256) void proj_gemm(
    const ushort_t* __restrict__ xb, const ushort_t* __restrict__ WqkvT,
    ushort_t* __restrict__ Qb, ushort_t* __restrict__ Kb,
    ushort_t* __restrict__ Vb) {
    __shared__ ushort_t As[128][PAD];
    __shared__ ushort_t Bs[128][PAD];
    int bid = blockIdx.x;
    int tileN = bid % 12, tileM = bid / 12;
    int tid = threadIdx.x;
    int w = tid >> 6, lane = tid & 63, q = lane >> 4, r = lane & 15;
    int wr = (w & 1) * 64, wc = (w >> 1) * 64;
    float4v acc[4][4];
    for (int i = 0; i < 4; i++)
        for (int j = 0; j < 4; j++)
            for (int e = 0; e < 4; e++) acc[i][j][e] = 0.f;

    for (int k0 = 0; k0 < 256; k0 += 64) {
        for (int it = 0; it < 4; it++) {
            int idx = tid + it * 256;
            int row = idx >> 3, kc = (idx & 7) * 8;
            *(short8*)&As[row][kc] =
                *(const short8*)&xb[(size_t)(tileM * 128 + row) * 256 + k0 + kc];
            *(short8*)&Bs[row][kc] =
                *(const short8*)&WqkvT[(size_t)(tileN * 128 + row) * 256 + k0 + kc];
        }
        __syncthreads();
        for (int kk = 0; kk < 64; kk += 32) {
            short8 a[4], b[4];
            for (int mi = 0; mi < 4; mi++)
                a[mi] = *(const short8*)&As[wr + mi * 16 + r][kk + q * 8];
            for (int ni = 0; ni < 4; ni++)
                b[ni] = *(const short8*)&Bs[wc + ni * 16 + r][kk + q * 8];
            for (int mi = 0; mi < 4; mi++)
                for (int ni = 0; ni < 4; ni++)
                    acc[mi][ni] = __builtin_amdgcn_mfma_f32_16x16x32_bf16(
                        a[mi], b[ni], acc[mi][ni], 0, 0, 0);
        }
        __syncthreads();
    }
    for (int mi = 0; mi < 4; mi++)
        for (int ni = 0; ni < 4; ni++)
            for (int reg = 0; reg < 4; reg++) {
                int grow = tileM * 128 + wr + mi * 16 + q * 4 + reg;
                int gcol = tileN * 128 + wc + ni * 16 + r;
                float v = acc[mi][ni][reg];
                int which = gcol >> 9, inner = gcol & 511;
                int h = inner >> 6, d = inner & 63;
                int b = grow >> 12, n = grow & 4095;
                size_t off = (((size_t)(b * H_ + h)) * N_ + n) * DH_ + d;
                if (which == 0) Qb[off] = f2bf(v);
                else if (which == 1) Kb[off] = f2bf(v);
                else Vb[off] = f2bf(v);
            }
}

// ---------------- per-head LayerNorm + y init + transposed fp8 t0 -----------
__global__ __launch_bounds__(256) void ln_kernel(
    const ushort_t* __restrict__ Vb, const float* __restrict__ gamma,
    const float* __restrict__ beta, const float* __restrict__ coeffs,
    unsigned char* __restrict__ t0T, float* __restrict__ y) {
    int tid = threadIdx.x;
    int wave = tid >> 6, lane = tid & 63;
    size_t row = (size_t)blockIdx.x * 4 + wave;   // bh*4096 + n
    int bh = (int)(row >> 12), n = (int)(row & 4095);
    int h = bh & 7;
    float v = bf2f(Vb[row * 64 + lane]);
    float s = v;
    for (int m = 32; m >= 1; m >>= 1) s += __shfl_xor(s, m, 64);
    float mu = s * (1.f / 64.f);
    float dv = v - mu;
    float s2 = dv * dv;
    for (int m = 32; m >= 1; m >>= 1) s2 += __shfl_xor(s2, m, 64);
    float var = s2 * (1.f / 64.f);
    float vln = dv * rsqrtf(var + 1e-5f) * gamma[lane] + beta[lane];
    float c0 = coeffs[h * 4 + 0];
    y[row * 64 + lane] = c0 * vln;
    t0T[((size_t)bh * 64 + lane) * 4096 + n] = f2fp8s(vln);
}

// ---------------- fused flash-style polynomial pass -------------------------
// E = exp(QK^T/8) is NEVER materialized in HBM. Per block: 64 output rows,
// loop over 64-column chunks of the 4096-wide adjacency:
//   QK^T (bf16 MFMA, swapped A=K B=Q) -> exp -> fp8 pack in-register ->
//   fp8 filter MFMA (U += E*t, s += E*1) -> epilogue t=U/s, y += ck*t, t^T out.
// K rows are PERMUTED at LDS staging so that the swapped-QK output lands in
// lanes exactly matching the fp8 MFMA A-fragment layout (byte b of lane
// group q <-> phys j = 8q+b): phys row j -> LDS row
//   (j&32) + 16*((j>>2)&1) + (j&3) + 4*((j>>3)&3).
// Double-buffered K+t LDS, lgkmcnt-only barrier (global prefetches survive).

#define FMFMA(TsX, a0v, a1v)                                                    \
    {                                                                           \
        long b0 = *(const long*)&TsX[r][q * 8];                                 \
        long b1 = *(const long*)&TsX[16 + r][q * 8];                            \
        long b2 = *(const long*)&TsX[32 + r][q * 8];                            \
        long b3 = *(const long*)&TsX[48 + r][q * 8];                            \
        acc[0] = __builtin_amdgcn_mfma_f32_16x16x32_fp8_fp8(a0v, b0, acc[0], 0, 0, 0); \
        acc[1] = __builtin_amdgcn_mfma_f32_16x16x32_fp8_fp8(a0v, b1, acc[1], 0, 0, 0); \
        acc[2] = __builtin_amdgcn_mfma_f32_16x16x32_fp8_fp8(a0v, b2, acc[2], 0, 0, 0); \
        acc[3] = __builtin_amdgcn_mfma_f32_16x16x32_fp8_fp8(a0v, b3, acc[3], 0, 0, 0); \
        accs   = __builtin_amdgcn_mfma_f32_16x16x32_fp8_fp8(a0v, bones, accs, 0, 0, 0); \
        long c0 = *(const long*)&TsX[r][32 + q * 8];                            \
        long c1 = *(const long*)&TsX[16 + r][32 + q * 8];                       \
        long c2 = *(const long*)&TsX[32 + r][32 + q * 8];                       \
        long c3 = *(const long*)&TsX[48 + r][32 + q * 8];                       \
        acc[0] = __builtin_amdgcn_mfma_f32_16x16x32_fp8_fp8(a1v, c0, acc[0], 0, 0, 0); \
        acc[1] = __builtin_amdgcn_mfma_f32_16x16x32_fp8_fp8(a1v, c1, acc[1], 0, 0, 0); \
        acc[2] = __builtin_amdgcn_mfma_f32_16x16x32_fp8_fp8(a1v, c2, acc[2], 0, 0, 0); \
        acc[3] = __builtin_amdgcn_mfma_f32_16x16x32_fp8_fp8(a1v, c3, acc[3], 0, 0, 0); \
        accs   = __builtin_amdgcn_mfma_f32_16x16x32_fp8_fp8(a1v, bones, accs, 0, 0, 0); \
    }

#define WGBAR()                                                \
    do {                                                       \
        asm volatile("s_waitcnt lgkmcnt(0)" ::: "memory");     \
        __builtin_amdgcn_sched_barrier(0);                     \
        __builtin_amdgcn_s_barrier();                          \
        __builtin_amdgcn_sched_barrier(0);                     \
    } while (0)

// Per-chunk compute: 4 swapped-QK S-tiles (8 bf16 MFMA), exp+pack, fp8 filter.
#define COMPUTE(KsX, TsX)                                                       \
    {                                                                           \
        short8 a0, a1;                                                          \
        float4v st0 = zf, st1 = zf, st2 = zf, st3 = zf;                         \
        a0 = *(const short8*)&KsX[r][q * 8];                                    \
        a1 = *(const short8*)&KsX[r][32 + q * 8];                               \
        st0 = __builtin_amdgcn_mfma_f32_16x16x32_bf16(a0, qf0, st0, 0, 0, 0);   \
        st0 = __builtin_amdgcn_mfma_f32_16x16x32_bf16(a1, qf1, st0, 0, 0, 0);   \
        a0 = *(const short8*)&KsX[16 + r][q * 8];                               \
        a1 = *(const short8*)&KsX[16 + r][32 + q * 8];                          \
        st1 = __builtin_amdgcn_mfma_f32_16x16x32_bf16(a0, qf0, st1, 0, 0, 0);   \
        st1 = __builtin_amdgcn_mfma_f32_16x16x32_bf16(a1, qf1, st1, 0, 0, 0);   \
        a0 = *(const short8*)&KsX[32 + r][q * 8];                               \
        a1 = *(const short8*)&KsX[32 + r][32 + q * 8];                          \
        st2 = __builtin_amdgcn_mfma_f32_16x16x32_bf16(a0, qf0, st2, 0, 0, 0);   \
        st2 = __builtin_amdgcn_mfma_f32_16x16x32_bf16(a1, qf1, st2, 0, 0, 0);   \
        a0 = *(const short8*)&KsX[48 + r][q * 8];                               \
        a1 = *(const short8*)&KsX[48 + r][32 + q * 8];                          \
        st3 = __builtin_amdgcn_mfma_f32_16x16x32_bf16(a0, qf0, st3, 0, 0, 0);   \
        st3 = __builtin_amdgcn_mfma_f32_16x16x32_bf16(a1, qf1, st3, 0, 0, 0);   \
        int d0 = __builtin_amdgcn_cvt_pk_fp8_f32(                               \
            __expf(0.125f * st0[0]), __expf(0.125f * st0[1]), 0, false);        \
        d0 = __builtin_amdgcn_cvt_pk_fp8_f32(                                   \
            __expf(0.125f * st0[2]), __expf(0.125f * st0[3]), d0, true);        \
        int d1 = __builtin_amdgcn_cvt_pk_fp8_f32(                               \
            __expf(0.125f * st1[0]), __expf(0.125f * st1[1]), 0, false);        \
        d1 = __builtin_amdgcn_cvt_pk_fp8_f32(                                   \
            __expf(0.125f * st1[2]), __expf(0.125f * st1[3]), d1, true);        \
        long eAv = (long)(((unsigned long)(unsigned int)d1 << 32) |             \
                          (unsigned int)d0);                                    \
        d0 = __builtin_amdgcn_cvt_pk_fp8_f32(                                   \
            __expf(0.125f * st2[0]), __expf(0.125f * st2[1]), 0, false);        \
        d0 = __builtin_amdgcn_cvt_pk_fp8_f32(                                   \
            __expf(0.125f * st2[2]), __expf(0.125f * st2[3]), d0, true);        \
        d1 = __builtin_amdgcn_cvt_pk_fp8_f32(                                   \
            __expf(0.125f * st3[0]), __expf(0.125f * st3[1]), 0, false);        \
        d1 = __builtin_amdgcn_cvt_pk_fp8_f32(                                   \
            __expf(0.125f * st3[2]), __expf(0.125f * st3[3]), d1, true);        \
        long eBv = (long)(((unsigned long)(unsigned int)d1 << 32) |             \
                          (unsigned int)d0);                                    \
        FMFMA(TsX, eAv, eBv);                                                   \
    }

__global__ __launch_bounds__(256) void poly_pass(
    const ushort_t* __restrict__ Qb, const ushort_t* __restrict__ Kb,
    const unsigned char* __restrict__ tinT, float* __restrict__ y,
    unsigned char* __restrict__ toutT, const float* __restrict__ coeffs,
    int kidx, int write_t) {
    __shared__ ushort_t Ks0[64][PAD];
    __shared__ ushort_t Ks1[64][PAD];
    __shared__ unsigned char Ts0[64][FPAD];
    __shared__ unsigned char Ts1[64][FPAD];
    int bid0 = blockIdx.x;
    // XCD-chunked swizzle: 1024 blocks, 8 XCDs -> each XCD gets 2 contiguous bh
    int bid = ((bid0 & 7) << 7) | (bid0 >> 3);
    int bh = bid >> 6, ti = bid & 63;
    const ushort_t* Q = Qb + (size_t)bh * N_ * 64;
    const ushort_t* K = Kb + (size_t)bh * N_ * 64;
    const unsigned char* tin = tinT + (size_t)bh * 64 * N_;
    int tid = threadIdx.x, w = tid >> 6, lane = tid & 63, q = lane >> 4, r = lane & 15;
    const float4v zf = {0.f, 0.f, 0.f, 0.f};

    // Q fragments in registers for the whole k-loop (B-operand of swapped QK)
    const ushort_t* qp = Q + (size_t)(ti * 64 + w * 16 + r) * 64 + q * 8;
    short8 qf0 = *(const short8*)qp;          // d = q*8 .. q*8+7
    short8 qf1 = *(const short8*)(qp + 32);   // d = 32+q*8 ..

    float4v acc[4], accs;
    for (int e = 0; e < 4; e++) accs[e] = 0.f;
    for (int j = 0; j < 4; j++)
        for (int e = 0; e < 4; e++) acc[j][e] = 0.f;
    const long bones = 0x3838383838383838L;  // 8x fp8(1.0)

    // staging maps
    int krow = tid >> 2, kpart = (tid & 3) * 16;          // K: 16 bf16 (32B)/thread
    int Lrow = (krow & 32) + ((krow & 4) << 2) + (krow & 3) + ((krow >> 3) & 3) * 4;
    const ushort_t* kp = K + (size_t)krow * 64 + kpart;
    int srow = tid >> 2, scol = (tid & 3) * 16;           // t: 16B/thread
    const unsigned char* tp = tin + (size_t)srow * 4096 + scol;

    // prologue: stage chunk0, prefetch chunk1 into regs
    {
        uint4v ka = *(const uint4v*)kp;
        uint4v kb = *(const uint4v*)(kp + 8);
        uint4v tv = *(const uint4v*)tp;
        *(uint4v*)&Ks0[Lrow][kpart] = ka;
        *(uint4v*)&Ks0[Lrow][kpart + 8] = kb;
        *(uint4v*)&Ts0[srow][scol] = tv;
    }
    uint4v pka = *(const uint4v*)(kp + 4096);
    uint4v pkb = *(const uint4v*)(kp + 4096 + 8);
    uint4v pt  = *(const uint4v*)(tp + 64);
    WGBAR();

    for (int it = 0; it < 64; it += 2) {
        // ---- phase A: compute chunk it from buf0; stage buf1 <- chunk it+1
        *(uint4v*)&Ks1[Lrow][kpart] = pka;
        *(uint4v*)&Ks1[Lrow][kpart + 8] = pkb;
        *(uint4v*)&Ts1[srow][scol] = pt;
        if (it + 2 < 64) {
            pka = *(const uint4v*)(kp + (size_t)(it + 2) * 4096);
            pkb = *(const uint4v*)(kp + (size_t)(it + 2) * 4096 + 8);
            pt  = *(const uint4v*)(tp + (size_t)(it + 2) * 64);
        }
        COMPUTE(Ks0, Ts0);
        WGBAR();
        // ---- phase B: compute chunk it+1 from buf1; stage buf0 <- chunk it+2
        *(uint4v*)&Ks0[Lrow][kpart] = pka;
        *(uint4v*)&Ks0[Lrow][kpart + 8] = pkb;
        *(uint4v*)&Ts0[srow][scol] = pt;
        if (it + 3 < 64) {
            pka = *(const uint4v*)(kp + (size_t)(it + 3) * 4096);
            pkb = *(const uint4v*)(kp + (size_t)(it + 3) * 4096 + 8);
            pt  = *(const uint4v*)(tp + (size_t)(it + 3) * 64);
        }
        COMPUTE(Ks1, Ts1);
        WGBAR();
    }

    // ---- epilogue: normalize, y += ck*t, fp8 t^T via LDS bounce ----
    int h = bh & 7;
    float ck = coeffs[h * 4 + kidx];
    float rinv[4];
#pragma unroll
    for (int reg = 0; reg < 4; reg++) rinv[reg] = 1.f / accs[reg];
    float tv[4][4];
#pragma unroll
    for (int ni = 0; ni < 4; ni++)
#pragma unroll
        for (int reg = 0; reg < 4; reg++)
            tv[ni][reg] = acc[ni][reg] * rinv[reg];
#pragma unroll
    for (int reg = 0; reg < 4; reg++) {
        int il = w * 16 + q * 4 + reg;
        float* yp = y + ((size_t)bh * N_ + (size_t)ti * 64 + il) * 64;
#pragma unroll
        for (int ni = 0; ni < 4; ni++)
            yp[ni * 16 + r] += ck * tv[ni][reg];
    }
    if (write_t) {
        // all waves are past the loop's final barrier -> safe to reuse Ts0
        unsigned char (*TT)[FPAD] = Ts0;   // TT[d][n_local]
#pragma unroll
        for (int ni = 0; ni < 4; ni++) {
            int p = __builtin_amdgcn_cvt_pk_fp8_f32(tv[ni][0], tv[ni][1], 0, false);
            p = __builtin_amdgcn_cvt_pk_fp8_f32(tv[ni][2], tv[ni][3], p, true);
            *(unsigned int*)&TT[ni * 16 + r][w * 16 + q * 4] = (unsigned int)p;
        }
        WGBAR();
        int drow = tid >> 2, dcol = (tid & 3) * 16;
        uint4v vv = *(const uint4v*)&TT[drow][dcol];
        *(uint4v*)&toutT[(size_t)bh * 64 * N_ + (size_t)drow * N_ + ti * 64 + dcol] = vv;
    }
}

// ---------------- output projection: merged[8192,512] x Wo[512,256] ---------
__global__ __launch_bounds__(256) void out_gemm(
    const float* __restrict__ y, const ushort_t* __restrict__ WoT,
    float* __restrict__ out) {
    __shared__ ushort_t As[128][PAD];
    __shared__ ushort_t Bs[64][PAD];
    int bid = blockIdx.x;
    int tileN = bid & 3, tileM = bid >> 2;
    int tid = threadIdx.x, w = tid >> 6, lane = tid & 63, q = lane >> 4, r = lane & 15;
    int wr = w * 32;
    float4v acc[2][4];
    for (int i = 0; i < 2; i++)
        for (int j = 0; j < 4; j++)
            for (int e = 0; e < 4; e++) acc[i][j][e] = 0.f;

    for (int k0 = 0; k0 < 512; k0 += 64) {
        int h = k0 >> 6;
        for (int it = 0; it < 8; it++) {
            int idx = tid + it * 256;
            int row = idx >> 4, kc = (idx & 15) * 4;
            int grow = tileM * 128 + row;
            int b = grow >> 12, n = grow & 4095;
            const float4* src =
                (const float4*)&y[(((size_t)(b * H_ + h)) * N_ + n) * 64 + kc];
            float4 v = *src;
            ushort4v pv;
            pv[0] = f2bf(v.x); pv[1] = f2bf(v.y); pv[2] = f2bf(v.z); pv[3] = f2bf(v.w);
            *(ushort4v*)&As[row][kc] = pv;
        }
        for (int it = 0; it < 2; it++) {
            int idx = tid + it * 256;
            int row = idx >> 3, kc = (idx & 7) * 8;
            *(short8*)&Bs[row][kc] =
                *(const short8*)&WoT[(size_t)(tileN * 64 + row) * 512 + k0 + kc];
        }
        __syncthreads();
        for (int kk = 0; kk < 64; kk += 32) {
            short8 a[2], b[4];
            a[0] = *(const short8*)&As[wr + r][kk + q * 8];
            a[1] = *(const short8*)&As[wr + 16 + r][kk + q * 8];
            for (int ni = 0; ni < 4; ni++)
                b[ni] = *(const short8*)&Bs[ni * 16 + r][kk + q * 8];
            for (int mi = 0; mi < 2; mi++)
                for (int ni = 0; ni < 4; ni++)
                    acc[mi][ni] = __builtin_amdgcn_mfma_f32_16x16x32_bf16(
                        a[mi], b[ni], acc[mi][ni], 0, 0, 0);
        }
        __syncthreads();
    }
    for (int mi = 0; mi < 2; mi++)
        for (int reg = 0; reg < 4; reg++) {
            int grow = tileM * 128 + wr + mi * 16 + q * 4 + reg;
            for (int ni = 0; ni < 4; ni++) {
                int gcol = tileN * 64 + ni * 16 + r;
                out[(size_t)grow * 256 + gcol] = acc[mi][ni][reg];
            }
        }
}

// ---------------------------------------------------------------------------
extern "C" void kernel_launch(void* const* d_in, const int* in_sizes, int n_in,
                              void* d_out, int out_size, void* d_ws, size_t ws_size,
                              hipStream_t stream) {
    const float* x      = (const float*)d_in[0];
    const float* Wq     = (const float*)d_in[1];
    const float* Wk     = (const float*)d_in[2];
    const float* Wv     = (const float*)d_in[3];
    const float* Wo     = (const float*)d_in[4];
    const float* gamma  = (const float*)d_in[5];
    const float* beta   = (const float*)d_in[6];
    const float* coeffs = (const float*)d_in[7];
    float* out = (float*)d_out;

    char* ws = (char*)d_ws;
    size_t off = 0;
    auto alloc = [&](size_t bytes) -> void* {
        void* p = ws + off;
        off += (bytes + 255) & ~(size_t)255;
        return p;
    };
    ushort_t* xb    = (ushort_t*)alloc((size_t)B_ * N_ * D_ * 2);
    ushort_t* WqkvT = (ushort_t*)alloc((size_t)3 * INNER_ * D_ * 2);
    ushort_t* WoT   = (ushort_t*)alloc((size_t)D_ * INNER_ * 2);
    ushort_t* Qb    = (ushort_t*)alloc((size_t)NBH * N_ * DH_ * 2);
    ushort_t* Kb    = (ushort_t*)alloc((size_t)NBH * N_ * DH_ * 2);
    ushort_t* Vb    = (ushort_t*)alloc((size_t)NBH * N_ * DH_ * 2);
    unsigned char* t0T = (unsigned char*)alloc((size_t)NBH * DH_ * N_);
    unsigned char* t1T = (unsigned char*)alloc((size_t)NBH * DH_ * N_);
    float*    y     = (float*)alloc((size_t)NBH * N_ * DH_ * 4);

    const int prep_total = B_ * N_ * D_ + 3 * INNER_ * D_ + D_ * INNER_;
    prep_kernel<<<(prep_total + 255) / 256, 256, 0, stream>>>(
        x, Wq, Wk, Wv, Wo, xb, WqkvT, WoT);
    proj_gemm<<<768, 256, 0, stream>>>(xb, WqkvT, Qb, Kb, Vb);
    ln_kernel<<<(NBH * N_) / 4, 256, 0, stream>>>(Vb, gamma, beta, coeffs, t0T, y);

    poly_pass<<<NBH * 64, 256, 0, stream>>>(Qb, Kb, t0T, y, t1T, coeffs, 1, 1);
    poly_pass<<<NBH * 64, 256, 0, stream>>>(Qb, Kb, t1T, y, t0T, coeffs, 2, 1);
    poly_pass<<<NBH * 64, 256, 0, stream>>>(Qb, Kb, t0T, y, t1T, coeffs, 3, 0);

    out_gemm<<<256, 256, 0, stream>>>(y, WoT, out);
}

// Round 3
// 391.727 us; speedup vs baseline: 1.3169x; 1.0828x over previous
//
#include <hip/hip_runtime.h>
#include <stdint.h>

#define B_ 2
#define N_ 4096
#define D_ 256
#define H_ 8
#define DH_ 64
#define INNER_ 512
#define NBH 16
#define PAD 72
#define FPAD 80

typedef unsigned short ushort_t;
typedef __attribute__((ext_vector_type(8))) short short8;
typedef __attribute__((ext_vector_type(4))) float float4v;
typedef __attribute__((ext_vector_type(4))) unsigned short ushort4v;
typedef __attribute__((ext_vector_type(4))) unsigned int uint4v;

__device__ __forceinline__ ushort_t f2bf(float f) {
    union { float f; unsigned int u; } v; v.f = f;
    unsigned int r = v.u + 0x7FFFu + ((v.u >> 16) & 1u);
    return (ushort_t)(r >> 16);
}
__device__ __forceinline__ float bf2f(ushort_t u) {
    union { unsigned int u; float f; } v; v.u = ((unsigned int)u) << 16;
    return v.f;
}
// full signed fp8 e4m3 encode with subnormal + clamp handling (for t values)
__device__ __forceinline__ unsigned char f2fp8s(float f) {
    union { float f; unsigned int u; } v; v.f = f;
    unsigned int s = (v.u >> 24) & 0x80u;
    v.u &= 0x7FFFFFFFu;
    float a = v.f;
    if (a >= 448.f) return (unsigned char)(s | 0x7E);
    if (a < 0.015625f) {
        int m = (int)(a * 512.f + 0.5f);
        return (unsigned char)(s | (unsigned)m);
    }
    unsigned int u = v.u + 0x7FFFFu + ((v.u >> 20) & 1u);
    return (unsigned char)(s | (((u >> 20) & 0x7FF) - 960));
}
// 2^x via v_exp_f32; s_nop covers the trans->VALU wait state since the
// consumer (cvt_pk) is compiler-emitted and can land immediately after.
__device__ __forceinline__ float fexp2(float x) {
    float r;
    asm volatile("v_exp_f32 %0, %1\n\ts_nop 0" : "=v"(r) : "v"(x));
    return r;
}

// ---------------- prep: bf16 conversions + weight transposes ----------------
__global__ __launch_bounds__(256) void prep_kernel(
    const float* __restrict__ x, const float* __restrict__ Wq,
    const float* __restrict__ Wk, const float* __restrict__ Wv,
    const float* __restrict__ Wo,
    ushort_t* __restrict__ xb, ushort_t* __restrict__ WqkvT,
    ushort_t* __restrict__ WoT) {
    int idx = blockIdx.x * 256 + threadIdx.x;
    const int total_x = B_ * N_ * D_;
    const int total_wqkv = 3 * INNER_ * D_;
    const int total_wo = D_ * INNER_;
    if (idx < total_x) { xb[idx] = f2bf(x[idx]); return; }
    idx -= total_x;
    if (idx < total_wqkv) {
        int n = idx >> 8, k = idx & 255;
        int which = n >> 9, nn = n & 511;
        const float* W = (which == 0) ? Wq : ((which == 1) ? Wk : Wv);
        WqkvT[idx] = f2bf(W[k * INNER_ + nn]);
        return;
    }
    idx -= total_wqkv;
    if (idx < total_wo) {
        int c = idx >> 9, k = idx & 511;
        WoT[idx] = f2bf(Wo[k * D_ + c]);
    }
}

// ---------------- fused QKV projection GEMM: [8192,256] x [256,1536] --------
// Q is pre-scaled by 0.125*log2(e) so the poly pass can use raw v_exp_f32.
__global__ __launch_bounds__(256) void proj_gemm(
    const ushort_t* __restrict__ xb, const ushort_t* __restrict__ WqkvT,
    ushort_t* __restrict__ Qb, ushort_t* __restrict__ Kb,
    ushort_t* __restrict__ Vb) {
    __shared__ ushort_t As[128][PAD];
    __shared__ ushort_t Bs[128][PAD];
    int bid = blockIdx.x;
    int tileN = bid % 12, tileM = bid / 12;
    int tid = threadIdx.x;
    int w = tid >> 6, lane = tid & 63, q = lane >> 4, r = lane & 15;
    int wr = (w & 1) * 64, wc = (w >> 1) * 64;
    float4v acc[4][4];
    for (int i = 0; i < 4; i++)
        for (int j = 0; j < 4; j++)
            for (int e = 0; e < 4; e++) acc[i][j][e] = 0.f;

    for (int k0 = 0; k0 < 256; k0 += 64) {
        for (int it = 0; it < 4; it++) {
            int idx = tid + it * 256;
            int row = idx >> 3, kc = (idx & 7) * 8;
            *(short8*)&As[row][kc] =
                *(const short8*)&xb[(size_t)(tileM * 128 + row) * 256 + k0 + kc];
            *(short8*)&Bs[row][kc] =
                *(const short8*)&WqkvT[(size_t)(tileN * 128 + row) * 256 + k0 + kc];
        }
        __syncthreads();
        for (int kk = 0; kk < 64; kk += 32) {
            short8 a[4], b[4];
            for (int mi = 0; mi < 4; mi++)
                a[mi] = *(const short8*)&As[wr + mi * 16 + r][kk + q * 8];
            for (int ni = 0; ni < 4; ni++)
                b[ni] = *(const short8*)&Bs[wc + ni * 16 + r][kk + q * 8];
            for (int mi = 0; mi < 4; mi++)
                for (int ni = 0; ni < 4; ni++)
                    acc[mi][ni] = __builtin_amdgcn_mfma_f32_16x16x32_bf16(
                        a[mi], b[ni], acc[mi][ni], 0, 0, 0);
        }
        __syncthreads();
    }
    for (int mi = 0; mi < 4; mi++)
        for (int ni = 0; ni < 4; ni++)
            for (int reg = 0; reg < 4; reg++) {
                int grow = tileM * 128 + wr + mi * 16 + q * 4 + reg;
                int gcol = tileN * 128 + wc + ni * 16 + r;
                float v = acc[mi][ni][reg];
                int which = gcol >> 9, inner = gcol & 511;
                int h = inner >> 6, d = inner & 63;
                int b = grow >> 12, n = grow & 4095;
                size_t off = (((size_t)(b * H_ + h)) * N_ + n) * DH_ + d;
                if (which == 0) Qb[off] = f2bf(v * 0.18033688011112042f);
                else if (which == 1) Kb[off] = f2bf(v);
                else Vb[off] = f2bf(v);
            }
}

// ---------------- per-head LayerNorm + y init + transposed fp8 t0 -----------
__global__ __launch_bounds__(256) void ln_kernel(
    const ushort_t* __restrict__ Vb, const float* __restrict__ gamma,
    const float* __restrict__ beta, const float* __restrict__ coeffs,
    unsigned char* __restrict__ t0T, float* __restrict__ y) {
    int tid = threadIdx.x;
    int wave = tid >> 6, lane = tid & 63;
    size_t row = (size_t)blockIdx.x * 4 + wave;   // bh*4096 + n
    int bh = (int)(row >> 12), n = (int)(row & 4095);
    int h = bh & 7;
    float v = bf2f(Vb[row * 64 + lane]);
    float s = v;
    for (int m = 32; m >= 1; m >>= 1) s += __shfl_xor(s, m, 64);
    float mu = s * (1.f / 64.f);
    float dv = v - mu;
    float s2 = dv * dv;
    for (int m = 32; m >= 1; m >>= 1) s2 += __shfl_xor(s2, m, 64);
    float var = s2 * (1.f / 64.f);
    float vln = dv * rsqrtf(var + 1e-5f) * gamma[lane] + beta[lane];
    float c0 = coeffs[h * 4 + 0];
    y[row * 64 + lane] = c0 * vln;
    t0T[((size_t)bh * 64 + lane) * 4096 + n] = f2fp8s(vln);
}

// ---------------- fused flash-style polynomial pass (32 rows / wave) --------
// Block = 128 output rows (4 waves x 32), full k=4096 sweep, E never in HBM.
// LDS traffic per output halved vs 16-row version: the K A-fragments and the
// t B-fragments are SHARED between the two 16-row i-halves of each wave.
// K rows permuted at staging (phys j -> Lrow = (j&32)+16*((j>>2)&1)+(j&3)
// +4*((j>>3)&3)) so swapped-QK output packs straight into fp8 A-fragments.
// Prefetch guards removed (bounded overrun into the next ws buffer is safe).

#define MFB(a, b, c) __builtin_amdgcn_mfma_f32_16x16x32_bf16(a, b, c, 0, 0, 0)
#define MFP(a, b, c) __builtin_amdgcn_mfma_f32_16x16x32_fp8_fp8(a, b, c, 0, 0, 0)

__device__ __forceinline__ long pk8(float4v x, float4v y) {
    int d0 = __builtin_amdgcn_cvt_pk_fp8_f32(fexp2(x[0]), fexp2(x[1]), 0, false);
    d0 = __builtin_amdgcn_cvt_pk_fp8_f32(fexp2(x[2]), fexp2(x[3]), d0, true);
    int d1 = __builtin_amdgcn_cvt_pk_fp8_f32(fexp2(y[0]), fexp2(y[1]), 0, false);
    d1 = __builtin_amdgcn_cvt_pk_fp8_f32(fexp2(y[2]), fexp2(y[3]), d1, true);
    return (long)(((unsigned long)(unsigned int)d1 << 32) | (unsigned int)d0);
}

#define WGBAR()                                                \
    do {                                                       \
        asm volatile("s_waitcnt lgkmcnt(0)" ::: "memory");     \
        __builtin_amdgcn_sched_barrier(0);                     \
        __builtin_amdgcn_s_barrier();                          \
        __builtin_amdgcn_sched_barrier(0);                     \
    } while (0)

#define COMPUTE32(KsX, TsX)                                                     \
    {                                                                           \
        short8 a0, a1;                                                          \
        float4v s00, s10, s20, s30, s01, s11, s21, s31;                         \
        a0 = *(const short8*)&KsX[r][q * 8];                                    \
        a1 = *(const short8*)&KsX[r][32 + q * 8];                               \
        s00 = MFB(a1, qf1, MFB(a0, qf0, zf));                                   \
        s01 = MFB(a1, qf3, MFB(a0, qf2, zf));                                   \
        a0 = *(const short8*)&KsX[16 + r][q * 8];                               \
        a1 = *(const short8*)&KsX[16 + r][32 + q * 8];                          \
        s10 = MFB(a1, qf1, MFB(a0, qf0, zf));                                   \
        s11 = MFB(a1, qf3, MFB(a0, qf2, zf));                                   \
        a0 = *(const short8*)&KsX[32 + r][q * 8];                               \
        a1 = *(const short8*)&KsX[32 + r][32 + q * 8];                          \
        s20 = MFB(a1, qf1, MFB(a0, qf0, zf));                                   \
        s21 = MFB(a1, qf3, MFB(a0, qf2, zf));                                   \
        a0 = *(const short8*)&KsX[48 + r][q * 8];                               \
        a1 = *(const short8*)&KsX[48 + r][32 + q * 8];                          \
        s30 = MFB(a1, qf1, MFB(a0, qf0, zf));                                   \
        s31 = MFB(a1, qf3, MFB(a0, qf2, zf));                                   \
        long eA0 = pk8(s00, s10), eB0 = pk8(s20, s30);                          \
        long eA1 = pk8(s01, s11), eB1 = pk8(s21, s31);                          \
        long b0 = *(const long*)&TsX[r][q * 8];                                 \
        long b1 = *(const long*)&TsX[16 + r][q * 8];                            \
        long b2 = *(const long*)&TsX[32 + r][q * 8];                            \
        long b3 = *(const long*)&TsX[48 + r][q * 8];                            \
        acc0[0] = MFP(eA0, b0, acc0[0]); acc1[0] = MFP(eA1, b0, acc1[0]);       \
        acc0[1] = MFP(eA0, b1, acc0[1]); acc1[1] = MFP(eA1, b1, acc1[1]);       \
        acc0[2] = MFP(eA0, b2, acc0[2]); acc1[2] = MFP(eA1, b2, acc1[2]);       \
        acc0[3] = MFP(eA0, b3, acc0[3]); acc1[3] = MFP(eA1, b3, acc1[3]);       \
        accs0 = MFP(eA0, bones, accs0);  accs1 = MFP(eA1, bones, accs1);        \
        b0 = *(const long*)&TsX[r][32 + q * 8];                                 \
        b1 = *(const long*)&TsX[16 + r][32 + q * 8];                            \
        b2 = *(const long*)&TsX[32 + r][32 + q * 8];                            \
        b3 = *(const long*)&TsX[48 + r][32 + q * 8];                            \
        acc0[0] = MFP(eB0, b0, acc0[0]); acc1[0] = MFP(eB1, b0, acc1[0]);       \
        acc0[1] = MFP(eB0, b1, acc0[1]); acc1[1] = MFP(eB1, b1, acc1[1]);       \
        acc0[2] = MFP(eB0, b2, acc0[2]); acc1[2] = MFP(eB1, b2, acc1[2]);       \
        acc0[3] = MFP(eB0, b3, acc0[3]); acc1[3] = MFP(eB1, b3, acc1[3]);       \
        accs0 = MFP(eB0, bones, accs0);  accs1 = MFP(eB1, bones, accs1);        \
    }

__global__ __launch_bounds__(256) void poly_pass(
    const ushort_t* __restrict__ Qb, const ushort_t* __restrict__ Kb,
    const unsigned char* __restrict__ tinT, float* __restrict__ y,
    unsigned char* __restrict__ toutT, const float* __restrict__ coeffs,
    int kidx, int write_t) {
    __shared__ ushort_t Ks0[64][PAD];
    __shared__ ushort_t Ks1[64][PAD];
    __shared__ unsigned char Ts0[64][FPAD];
    __shared__ unsigned char Ts1[64][FPAD];
    int bid0 = blockIdx.x;
    // XCD-chunked swizzle: 512 blocks, 8 XCDs -> each XCD owns 2 contiguous bh
    int bid = ((bid0 & 7) << 6) | (bid0 >> 3);
    int bh = bid >> 5, ti = bid & 31;            // 32 tiles of 128 rows per bh
    const ushort_t* Q = Qb + (size_t)bh * N_ * 64;
    const ushort_t* K = Kb + (size_t)bh * N_ * 64;
    const unsigned char* tin = tinT + (size_t)bh * 64 * N_;
    int tid = threadIdx.x, w = tid >> 6, lane = tid & 63, q = lane >> 4, r = lane & 15;
    const float4v zf = {0.f, 0.f, 0.f, 0.f};

    // Q fragments for this wave's 32 rows (two 16-row i-halves), whole k-loop
    const ushort_t* qp = Q + (size_t)(ti * 128 + w * 32 + r) * 64 + q * 8;
    short8 qf0 = *(const short8*)qp;               // half0, d = q*8..
    short8 qf1 = *(const short8*)(qp + 32);        // half0, d = 32+q*8..
    short8 qf2 = *(const short8*)(qp + 16 * 64);   // half1
    short8 qf3 = *(const short8*)(qp + 16 * 64 + 32);

    float4v acc0[4], acc1[4], accs0, accs1;
    for (int e = 0; e < 4; e++) { accs0[e] = 0.f; accs1[e] = 0.f; }
    for (int j = 0; j < 4; j++)
        for (int e = 0; e < 4; e++) { acc0[j][e] = 0.f; acc1[j][e] = 0.f; }
    const long bones = 0x3838383838383838L;  // 8x fp8(1.0)

    // staging maps (256 threads)
    int krow = tid >> 2, kpart = (tid & 3) * 16;          // K: 32B/thread
    int Lrow = (krow & 32) + ((krow & 4) << 2) + (krow & 3) + ((krow >> 3) & 3) * 4;
    const ushort_t* kp = K + (size_t)krow * 64 + kpart;
    int srow = tid >> 2, scol = (tid & 3) * 16;           // t: 16B/thread
    const unsigned char* tp = tin + (size_t)srow * 4096 + scol;

    // prologue: stage chunk0, hold chunk1 in regs, running load pointers at 2
    {
        uint4v ka = *(const uint4v*)kp;
        uint4v kb = *(const uint4v*)(kp + 8);
        uint4v tv = *(const uint4v*)tp;
        *(uint4v*)&Ks0[Lrow][kpart] = ka;
        *(uint4v*)&Ks0[Lrow][kpart + 8] = kb;
        *(uint4v*)&Ts0[srow][scol] = tv;
    }
    uint4v pka = *(const uint4v*)(kp + 4096);
    uint4v pkb = *(const uint4v*)(kp + 4096 + 8);
    uint4v pt  = *(const uint4v*)(tp + 64);
    const ushort_t* kpl = kp + 2 * 4096;
    const unsigned char* tpl = tp + 2 * 64;
    WGBAR();

    for (int it = 0; it < 64; it += 2) {
        // phase A: compute chunk it (buf0); stage buf1 <- chunk it+1; load it+2
        *(uint4v*)&Ks1[Lrow][kpart] = pka;
        *(uint4v*)&Ks1[Lrow][kpart + 8] = pkb;
        *(uint4v*)&Ts1[srow][scol] = pt;
        pka = *(const uint4v*)kpl;
        pkb = *(const uint4v*)(kpl + 8);
        pt  = *(const uint4v*)tpl;
        kpl += 4096; tpl += 64;
        COMPUTE32(Ks0, Ts0);
        WGBAR();
        // phase B: compute chunk it+1 (buf1); stage buf0 <- chunk it+2; load it+3
        *(uint4v*)&Ks0[Lrow][kpart] = pka;
        *(uint4v*)&Ks0[Lrow][kpart + 8] = pkb;
        *(uint4v*)&Ts0[srow][scol] = pt;
        pka = *(const uint4v*)kpl;
        pkb = *(const uint4v*)(kpl + 8);
        pt  = *(const uint4v*)tpl;
        kpl += 4096; tpl += 64;
        COMPUTE32(Ks1, Ts1);
        WGBAR();
    }

    // ---- epilogue: normalize, y += ck*t, fp8 t^T via LDS bounce ----
    int h = bh & 7;
    float ck = coeffs[h * 4 + kidx];
    float rinv0[4], rinv1[4];
#pragma unroll
    for (int reg = 0; reg < 4; reg++) {
        rinv0[reg] = 1.f / accs0[reg];
        rinv1[reg] = 1.f / accs1[reg];
    }
    float tv0[4][4], tv1[4][4];
#pragma unroll
    for (int ni = 0; ni < 4; ni++)
#pragma unroll
        for (int reg = 0; reg < 4; reg++) {
            tv0[ni][reg] = acc0[ni][reg] * rinv0[reg];
            tv1[ni][reg] = acc1[ni][reg] * rinv1[reg];
        }
#pragma unroll
    for (int reg = 0; reg < 4; reg++) {
        int il = w * 32 + q * 4 + reg;
        float* yp0 = y + ((size_t)bh * N_ + (size_t)ti * 128 + il) * 64;
        float* yp1 = yp0 + 16 * 64;
#pragma unroll
        for (int ni = 0; ni < 4; ni++) {
            yp0[ni * 16 + r] += ck * tv0[ni][reg];
            yp1[ni * 16 + r] += ck * tv1[ni][reg];
        }
    }
    if (write_t) {
        // all waves past the loop's final barrier -> safe to reuse Ks0 space
        unsigned char (*TT)[144] = (unsigned char(*)[144])&Ks0[0][0];  // [64 d][128 n]
#pragma unroll
        for (int ni = 0; ni < 4; ni++) {
            int p0 = __builtin_amdgcn_cvt_pk_fp8_f32(tv0[ni][0], tv0[ni][1], 0, false);
            p0 = __builtin_amdgcn_cvt_pk_fp8_f32(tv0[ni][2], tv0[ni][3], p0, true);
            *(unsigned int*)&TT[ni * 16 + r][w * 32 + q * 4] = (unsigned int)p0;
            int p1 = __builtin_amdgcn_cvt_pk_fp8_f32(tv1[ni][0], tv1[ni][1], 0, false);
            p1 = __builtin_amdgcn_cvt_pk_fp8_f32(tv1[ni][2], tv1[ni][3], p1, true);
            *(unsigned int*)&TT[ni * 16 + r][w * 32 + 16 + q * 4] = (unsigned int)p1;
        }
        WGBAR();
        int drow = tid >> 2, dcol = (tid & 3) * 32;
        uint4v v0 = *(const uint4v*)&TT[drow][dcol];
        uint4v v1 = *(const uint4v*)&TT[drow][dcol + 16];
        unsigned char* dst =
            toutT + (size_t)bh * 64 * N_ + (size_t)drow * N_ + ti * 128 + dcol;
        *(uint4v*)dst = v0;
        *(uint4v*)(dst + 16) = v1;
    }
}

// ---------------- output projection: merged[8192,512] x Wo[512,256] ---------
__global__ __launch_bounds__(256) void out_gemm(
    const float* __restrict__ y, const ushort_t* __restrict__ WoT,
    float* __restrict__ out) {
    __shared__ ushort_t As[128][PAD];
    __shared__ ushort_t Bs[64][PAD];
    int bid = blockIdx.x;
    int tileN = bid & 3, tileM = bid >> 2;
    int tid = threadIdx.x, w = tid >> 6, lane = tid & 63, q = lane >> 4, r = lane & 15;
    int wr = w * 32;
    float4v acc[2][4];
    for (int i = 0; i < 2; i++)
        for (int j = 0; j < 4; j++)
            for (int e = 0; e < 4; e++) acc[i][j][e] = 0.f;

    for (int k0 = 0; k0 < 512; k0 += 64) {
        int h = k0 >> 6;
        for (int it = 0; it < 8; it++) {
            int idx = tid + it * 256;
            int row = idx >> 4, kc = (idx & 15) * 4;
            int grow = tileM * 128 + row;
            int b = grow >> 12, n = grow & 4095;
            const float4* src =
                (const float4*)&y[(((size_t)(b * H_ + h)) * N_ + n) * 64 + kc];
            float4 v = *src;
            ushort4v pv;
            pv[0] = f2bf(v.x); pv[1] = f2bf(v.y); pv[2] = f2bf(v.z); pv[3] = f2bf(v.w);
            *(ushort4v*)&As[row][kc] = pv;
        }
        for (int it = 0; it < 2; it++) {
            int idx = tid + it * 256;
            int row = idx >> 3, kc = (idx & 7) * 8;
            *(short8*)&Bs[row][kc] =
                *(const short8*)&WoT[(size_t)(tileN * 64 + row) * 512 + k0 + kc];
        }
        __syncthreads();
        for (int kk = 0; kk < 64; kk += 32) {
            short8 a[2], b[4];
            a[0] = *(const short8*)&As[wr + r][kk + q * 8];
            a[1] = *(const short8*)&As[wr + 16 + r][kk + q * 8];
            for (int ni = 0; ni < 4; ni++)
                b[ni] = *(const short8*)&Bs[ni * 16 + r][kk + q * 8];
            for (int mi = 0; mi < 2; mi++)
                for (int ni = 0; ni < 4; ni++)
                    acc[mi][ni] = __builtin_amdgcn_mfma_f32_16x16x32_bf16(
                        a[mi], b[ni], acc[mi][ni], 0, 0, 0);
        }
        __syncthreads();
    }
    for (int mi = 0; mi < 2; mi++)
        for (int reg = 0; reg < 4; reg++) {
            int grow = tileM * 128 + wr + mi * 16 + q * 4 + reg;
            for (int ni = 0; ni < 4; ni++) {
                int gcol = tileN * 64 + ni * 16 + r;
                out[(size_t)grow * 256 + gcol] = acc[mi][ni][reg];
            }
        }
}

// ---------------------------------------------------------------------------
extern "C" void kernel_launch(void* const* d_in, const int* in_sizes, int n_in,
                              void* d_out, int out_size, void* d_ws, size_t ws_size,
                              hipStream_t stream) {
    const float* x      = (const float*)d_in[0];
    const float* Wq     = (const float*)d_in[1];
    const float* Wk     = (const float*)d_in[2];
    const float* Wv     = (const float*)d_in[3];
    const float* Wo     = (const float*)d_in[4];
    const float* gamma  = (const float*)d_in[5];
    const float* beta   = (const float*)d_in[6];
    const float* coeffs = (const float*)d_in[7];
    float* out = (float*)d_out;

    char* ws = (char*)d_ws;
    size_t off = 0;
    auto alloc = [&](size_t bytes) -> void* {
        void* p = ws + off;
        off += (bytes + 255) & ~(size_t)255;
        return p;
    };
    ushort_t* xb    = (ushort_t*)alloc((size_t)B_ * N_ * D_ * 2);
    ushort_t* WqkvT = (ushort_t*)alloc((size_t)3 * INNER_ * D_ * 2);
    ushort_t* WoT   = (ushort_t*)alloc((size_t)D_ * INNER_ * 2);
    ushort_t* Qb    = (ushort_t*)alloc((size_t)NBH * N_ * DH_ * 2);
    ushort_t* Kb    = (ushort_t*)alloc((size_t)NBH * N_ * DH_ * 2);
    ushort_t* Vb    = (ushort_t*)alloc((size_t)NBH * N_ * DH_ * 2);
    unsigned char* t0T = (unsigned char*)alloc((size_t)NBH * DH_ * N_);
    unsigned char* t1T = (unsigned char*)alloc((size_t)NBH * DH_ * N_);
    float*    y     = (float*)alloc((size_t)NBH * N_ * DH_ * 4);

    const int prep_total = B_ * N_ * D_ + 3 * INNER_ * D_ + D_ * INNER_;
    prep_kernel<<<(prep_total + 255) / 256, 256, 0, stream>>>(
        x, Wq, Wk, Wv, Wo, xb, WqkvT, WoT);
    proj_gemm<<<768, 256, 0, stream>>>(xb, WqkvT, Qb, Kb, Vb);
    ln_kernel<<<(NBH * N_) / 4, 256, 0, stream>>>(Vb, gamma, beta, coeffs, t0T, y);

    poly_pass<<<NBH * 32, 256, 0, stream>>>(Qb, Kb, t0T, y, t1T, coeffs, 1, 1);
    poly_pass<<<NBH * 32, 256, 0, stream>>>(Qb, Kb, t1T, y, t0T, coeffs, 2, 1);
    poly_pass<<<NBH * 32, 256, 0, stream>>>(Qb, Kb, t0T, y, t1T, coeffs, 3, 0);

    out_gemm<<<256, 256, 0, stream>>>(y, WoT, out);
}

// Round 4
// 361.192 us; speedup vs baseline: 1.4282x; 1.0845x over previous
//
#include <hip/hip_runtime.h>
#include <stdint.h>

#define B_ 2
#define N_ 4096
#define D_ 256
#define H_ 8
#define DH_ 64
#define INNER_ 512
#define NBH 16
#define PAD 72
#define FPAD 80

typedef unsigned short ushort_t;
typedef __attribute__((ext_vector_type(8))) short short8;
typedef __attribute__((ext_vector_type(4))) float float4v;
typedef __attribute__((ext_vector_type(4))) unsigned short ushort4v;
typedef __attribute__((ext_vector_type(4))) unsigned int uint4v;

__device__ __forceinline__ ushort_t f2bf(float f) {
    union { float f; unsigned int u; } v; v.f = f;
    unsigned int r = v.u + 0x7FFFu + ((v.u >> 16) & 1u);
    return (ushort_t)(r >> 16);
}
__device__ __forceinline__ float bf2f(ushort_t u) {
    union { unsigned int u; float f; } v; v.u = ((unsigned int)u) << 16;
    return v.f;
}
// full signed fp8 e4m3 encode with subnormal + clamp handling (for t values)
__device__ __forceinline__ unsigned char f2fp8s(float f) {
    union { float f; unsigned int u; } v; v.f = f;
    unsigned int s = (v.u >> 24) & 0x80u;
    v.u &= 0x7FFFFFFFu;
    float a = v.f;
    if (a >= 448.f) return (unsigned char)(s | 0x7E);
    if (a < 0.015625f) {
        int m = (int)(a * 512.f + 0.5f);
        return (unsigned char)(s | (unsigned)m);
    }
    unsigned int u = v.u + 0x7FFFFu + ((v.u >> 20) & 1u);
    return (unsigned char)(s | (((u >> 20) & 0x7FF) - 960));
}
// 2^x via v_exp_f32; s_nop covers the trans->VALU wait state.
__device__ __forceinline__ float fexp2(float x) {
    float r;
    asm volatile("v_exp_f32 %0, %1\n\ts_nop 0" : "=v"(r) : "v"(x));
    return r;
}

// ---------------- prep: bf16 conversions + weight transposes ----------------
__global__ __launch_bounds__(256) void prep_kernel(
    const float* __restrict__ x, const float* __restrict__ Wq,
    const float* __restrict__ Wk, const float* __restrict__ Wv,
    const float* __restrict__ Wo,
    ushort_t* __restrict__ xb, ushort_t* __restrict__ WqkvT,
    ushort_t* __restrict__ WoT) {
    int idx = blockIdx.x * 256 + threadIdx.x;
    const int total_x = B_ * N_ * D_;
    const int total_wqkv = 3 * INNER_ * D_;
    const int total_wo = D_ * INNER_;
    if (idx < total_x) { xb[idx] = f2bf(x[idx]); return; }
    idx -= total_x;
    if (idx < total_wqkv) {
        int n = idx >> 8, k = idx & 255;
        int which = n >> 9, nn = n & 511;
        const float* W = (which == 0) ? Wq : ((which == 1) ? Wk : Wv);
        WqkvT[idx] = f2bf(W[k * INNER_ + nn]);
        return;
    }
    idx -= total_wqkv;
    if (idx < total_wo) {
        int c = idx >> 9, k = idx & 511;
        WoT[idx] = f2bf(Wo[k * D_ + c]);
    }
}

// ---------------- fused QKV projection GEMM: [8192,256] x [256,1536] --------
// Q is pre-scaled by 0.125*log2(e) so the poly pass can use raw v_exp_f32.
__global__ __launch_bounds__(256) void proj_gemm(
    const ushort_t* __restrict__ xb, const ushort_t* __restrict__ WqkvT,
    ushort_t* __restrict__ Qb, ushort_t* __restrict__ Kb,
    ushort_t* __restrict__ Vb) {
    __shared__ ushort_t As[128][PAD];
    __shared__ ushort_t Bs[128][PAD];
    int bid = blockIdx.x;
    int tileN = bid % 12, tileM = bid / 12;
    int tid = threadIdx.x;
    int w = tid >> 6, lane = tid & 63, q = lane >> 4, r = lane & 15;
    int wr = (w & 1) * 64, wc = (w >> 1) * 64;
    float4v acc[4][4];
    for (int i = 0; i < 4; i++)
        for (int j = 0; j < 4; j++)
            for (int e = 0; e < 4; e++) acc[i][j][e] = 0.f;

    for (int k0 = 0; k0 < 256; k0 += 64) {
        for (int it = 0; it < 4; it++) {
            int idx = tid + it * 256;
            int row = idx >> 3, kc = (idx & 7) * 8;
            *(short8*)&As[row][kc] =
                *(const short8*)&xb[(size_t)(tileM * 128 + row) * 256 + k0 + kc];
            *(short8*)&Bs[row][kc] =
                *(const short8*)&WqkvT[(size_t)(tileN * 128 + row) * 256 + k0 + kc];
        }
        __syncthreads();
        for (int kk = 0; kk < 64; kk += 32) {
            short8 a[4], b[4];
            for (int mi = 0; mi < 4; mi++)
                a[mi] = *(const short8*)&As[wr + mi * 16 + r][kk + q * 8];
            for (int ni = 0; ni < 4; ni++)
                b[ni] = *(const short8*)&Bs[wc + ni * 16 + r][kk + q * 8];
            for (int mi = 0; mi < 4; mi++)
                for (int ni = 0; ni < 4; ni++)
                    acc[mi][ni] = __builtin_amdgcn_mfma_f32_16x16x32_bf16(
                        a[mi], b[ni], acc[mi][ni], 0, 0, 0);
        }
        __syncthreads();
    }
    for (int mi = 0; mi < 4; mi++)
        for (int ni = 0; ni < 4; ni++)
            for (int reg = 0; reg < 4; reg++) {
                int grow = tileM * 128 + wr + mi * 16 + q * 4 + reg;
                int gcol = tileN * 128 + wc + ni * 16 + r;
                float v = acc[mi][ni][reg];
                int which = gcol >> 9, inner = gcol & 511;
                int h = inner >> 6, d = inner & 63;
                int b = grow >> 12, n = grow & 4095;
                size_t off = (((size_t)(b * H_ + h)) * N_ + n) * DH_ + d;
                if (which == 0) Qb[off] = f2bf(v * 0.18033688011112042f);
                else if (which == 1) Kb[off] = f2bf(v);
                else Vb[off] = f2bf(v);
            }
}

// ---------------- per-head LayerNorm + y init + transposed fp8 t0 -----------
__global__ __launch_bounds__(256) void ln_kernel(
    const ushort_t* __restrict__ Vb, const float* __restrict__ gamma,
    const float* __restrict__ beta, const float* __restrict__ coeffs,
    unsigned char* __restrict__ t0T, float* __restrict__ y) {
    int tid = threadIdx.x;
    int wave = tid >> 6, lane = tid & 63;
    size_t row = (size_t)blockIdx.x * 4 + wave;   // bh*4096 + n
    int bh = (int)(row >> 12), n = (int)(row & 4095);
    int h = bh & 7;
    float v = bf2f(Vb[row * 64 + lane]);
    float s = v;
    for (int m = 32; m >= 1; m >>= 1) s += __shfl_xor(s, m, 64);
    float mu = s * (1.f / 64.f);
    float dv = v - mu;
    float s2 = dv * dv;
    for (int m = 32; m >= 1; m >>= 1) s2 += __shfl_xor(s2, m, 64);
    float var = s2 * (1.f / 64.f);
    float vln = dv * rsqrtf(var + 1e-5f) * gamma[lane] + beta[lane];
    float c0 = coeffs[h * 4 + 0];
    y[row * 64 + lane] = c0 * vln;
    t0T[((size_t)bh * 64 + lane) * 4096 + n] = f2fp8s(vln);
}

// ---------------- fused flash-style polynomial pass (8-wave k-split) --------
// Block = 128 output rows, 512 threads (8 waves). Waves 0-3 sweep k in
// [0,2048), waves 4-7 sweep [2048,4096) in an independent LDS stream ->
// 16 waves/CU (4/SIMD) for latency hiding with ZERO extra HBM traffic.
// Partial (u, rowsum) combined in LDS at the epilogue (half1 dumps, half0
// adds + normalizes + y += ck*t + fp8 t^T). E never touches HBM.
// K rows permuted at staging (phys j -> Lrow = (j&32)+16*((j>>2)&1)+(j&3)
// +4*((j>>3)&3)) so swapped-QK output packs straight into fp8 A-fragments.

#define MFB(a, b, c) __builtin_amdgcn_mfma_f32_16x16x32_bf16(a, b, c, 0, 0, 0)
#define MFP(a, b, c) __builtin_amdgcn_mfma_f32_16x16x32_fp8_fp8(a, b, c, 0, 0, 0)

__device__ __forceinline__ long pk8(float4v x, float4v y) {
    int d0 = __builtin_amdgcn_cvt_pk_fp8_f32(fexp2(x[0]), fexp2(x[1]), 0, false);
    d0 = __builtin_amdgcn_cvt_pk_fp8_f32(fexp2(x[2]), fexp2(x[3]), d0, true);
    int d1 = __builtin_amdgcn_cvt_pk_fp8_f32(fexp2(y[0]), fexp2(y[1]), 0, false);
    d1 = __builtin_amdgcn_cvt_pk_fp8_f32(fexp2(y[2]), fexp2(y[3]), d1, true);
    return (long)(((unsigned long)(unsigned int)d1 << 32) | (unsigned int)d0);
}

#define WGBAR()                                                \
    do {                                                       \
        asm volatile("s_waitcnt lgkmcnt(0)" ::: "memory");     \
        __builtin_amdgcn_sched_barrier(0);                     \
        __builtin_amdgcn_s_barrier();                          \
        __builtin_amdgcn_sched_barrier(0);                     \
    } while (0)

#define COMPUTE32(KsX, TsX)                                                     \
    {                                                                           \
        short8 a0, a1;                                                          \
        float4v s00, s10, s20, s30, s01, s11, s21, s31;                         \
        a0 = *(const short8*)&KsX[r][q * 8];                                    \
        a1 = *(const short8*)&KsX[r][32 + q * 8];                               \
        s00 = MFB(a1, qf1, MFB(a0, qf0, zf));                                   \
        s01 = MFB(a1, qf3, MFB(a0, qf2, zf));                                   \
        a0 = *(const short8*)&KsX[16 + r][q * 8];                               \
        a1 = *(const short8*)&KsX[16 + r][32 + q * 8];                          \
        s10 = MFB(a1, qf1, MFB(a0, qf0, zf));                                   \
        s11 = MFB(a1, qf3, MFB(a0, qf2, zf));                                   \
        a0 = *(const short8*)&KsX[32 + r][q * 8];                               \
        a1 = *(const short8*)&KsX[32 + r][32 + q * 8];                          \
        s20 = MFB(a1, qf1, MFB(a0, qf0, zf));                                   \
        s21 = MFB(a1, qf3, MFB(a0, qf2, zf));                                   \
        a0 = *(const short8*)&KsX[48 + r][q * 8];                               \
        a1 = *(const short8*)&KsX[48 + r][32 + q * 8];                          \
        s30 = MFB(a1, qf1, MFB(a0, qf0, zf));                                   \
        s31 = MFB(a1, qf3, MFB(a0, qf2, zf));                                   \
        long eA0 = pk8(s00, s10), eB0 = pk8(s20, s30);                          \
        long eA1 = pk8(s01, s11), eB1 = pk8(s21, s31);                          \
        long b0 = *(const long*)&TsX[r][q * 8];                                 \
        long b1 = *(const long*)&TsX[16 + r][q * 8];                            \
        long b2 = *(const long*)&TsX[32 + r][q * 8];                            \
        long b3 = *(const long*)&TsX[48 + r][q * 8];                            \
        acc0[0] = MFP(eA0, b0, acc0[0]); acc1[0] = MFP(eA1, b0, acc1[0]);       \
        acc0[1] = MFP(eA0, b1, acc0[1]); acc1[1] = MFP(eA1, b1, acc1[1]);       \
        acc0[2] = MFP(eA0, b2, acc0[2]); acc1[2] = MFP(eA1, b2, acc1[2]);       \
        acc0[3] = MFP(eA0, b3, acc0[3]); acc1[3] = MFP(eA1, b3, acc1[3]);       \
        accs0 = MFP(eA0, bones, accs0);  accs1 = MFP(eA1, bones, accs1);        \
        b0 = *(const long*)&TsX[r][32 + q * 8];                                 \
        b1 = *(const long*)&TsX[16 + r][32 + q * 8];                            \
        b2 = *(const long*)&TsX[32 + r][32 + q * 8];                            \
        b3 = *(const long*)&TsX[48 + r][32 + q * 8];                            \
        acc0[0] = MFP(eB0, b0, acc0[0]); acc1[0] = MFP(eB1, b0, acc1[0]);       \
        acc0[1] = MFP(eB0, b1, acc0[1]); acc1[1] = MFP(eB1, b1, acc1[1]);       \
        acc0[2] = MFP(eB0, b2, acc0[2]); acc1[2] = MFP(eB1, b2, acc1[2]);       \
        acc0[3] = MFP(eB0, b3, acc0[3]); acc1[3] = MFP(eB1, b3, acc1[3]);       \
        accs0 = MFP(eB0, bones, accs0);  accs1 = MFP(eB1, bones, accs1);        \
    }

__global__ __launch_bounds__(512, 4) void poly_pass(
    const ushort_t* __restrict__ Qb, const ushort_t* __restrict__ Kb,
    const unsigned char* __restrict__ tinT, float* __restrict__ y,
    unsigned char* __restrict__ toutT, const float* __restrict__ coeffs,
    int kidx, int write_t) {
    __shared__ char smem[57344];
    typedef ushort_t KsArr[64][PAD];
    typedef unsigned char TsArr[64][FPAD];
    KsArr* Ks0 = (KsArr*)smem;                     // [2][64][72] bf16 = 18432
    KsArr* Ks1 = (KsArr*)(smem + 18432);           // [2][64][72] bf16 = 18432
    TsArr* Ts0 = (TsArr*)(smem + 36864);           // [2][64][80] u8   = 10240
    TsArr* Ts1 = (TsArr*)(smem + 47104);           // [2][64][80] u8   = 10240

    int bid0 = blockIdx.x;
    // XCD-chunked swizzle: 512 blocks, 8 XCDs -> each XCD owns 2 contiguous bh
    int bid = ((bid0 & 7) << 6) | (bid0 >> 3);
    int bh = bid >> 5, ti = bid & 31;              // 32 tiles of 128 rows per bh
    const ushort_t* Q = Qb + (size_t)bh * N_ * 64;
    const ushort_t* K = Kb + (size_t)bh * N_ * 64;
    const unsigned char* tin = tinT + (size_t)bh * 64 * N_;
    int tid = threadIdx.x, w = tid >> 6, lane = tid & 63, q = lane >> 4, r = lane & 15;
    int half = w >> 2, wsub = w & 3;
    const float4v zf = {0.f, 0.f, 0.f, 0.f};

    // Q fragments for this wave's 32 rows (two 16-row i-halves), whole k-loop
    const ushort_t* qp = Q + (size_t)(ti * 128 + wsub * 32 + r) * 64 + q * 8;
    short8 qf0 = *(const short8*)qp;               // half0, d = q*8..
    short8 qf1 = *(const short8*)(qp + 32);        // half0, d = 32+q*8..
    short8 qf2 = *(const short8*)(qp + 16 * 64);   // half1
    short8 qf3 = *(const short8*)(qp + 16 * 64 + 32);

    float4v acc0[4], acc1[4], accs0, accs1;
    for (int e = 0; e < 4; e++) { accs0[e] = 0.f; accs1[e] = 0.f; }
    for (int j = 0; j < 4; j++)
        for (int e = 0; e < 4; e++) { acc0[j][e] = 0.f; acc1[j][e] = 0.f; }
    const long bones = 0x3838383838383838L;  // 8x fp8(1.0)

    // staging maps: threads 0-255 stage half0's stream, 256-511 half1's
    int tl = tid & 255;
    int krow = tl >> 2, kpart = (tl & 3) * 16;            // K: 32B/thread
    int Lrow = (krow & 32) + ((krow & 4) << 2) + (krow & 3) + ((krow >> 3) & 3) * 4;
    const ushort_t* kp = K + (size_t)(half * 2048 + krow) * 64 + kpart;
    int srow = tl >> 2, scol = (tl & 3) * 16;             // t: 16B/thread
    const unsigned char* tp = tin + (size_t)srow * 4096 + half * 2048 + scol;

    // prologue: stage chunk0, hold chunk1 in regs, running load pointers at 2
    {
        uint4v ka = *(const uint4v*)kp;
        uint4v kb = *(const uint4v*)(kp + 8);
        uint4v tv = *(const uint4v*)tp;
        *(uint4v*)&Ks0[half][Lrow][kpart] = ka;
        *(uint4v*)&Ks0[half][Lrow][kpart + 8] = kb;
        *(uint4v*)&Ts0[half][srow][scol] = tv;
    }
    uint4v pka = *(const uint4v*)(kp + 4096);
    uint4v pkb = *(const uint4v*)(kp + 4096 + 8);
    uint4v pt  = *(const uint4v*)(tp + 64);
    const ushort_t* kpl = kp + 2 * 4096;
    const unsigned char* tpl = tp + 2 * 64;
    WGBAR();

    for (int it = 0; it < 32; it += 2) {
        // phase A: compute chunk it (buf0); stage buf1 <- chunk it+1; load it+2
        *(uint4v*)&Ks1[half][Lrow][kpart] = pka;
        *(uint4v*)&Ks1[half][Lrow][kpart + 8] = pkb;
        *(uint4v*)&Ts1[half][srow][scol] = pt;
        pka = *(const uint4v*)kpl;
        pkb = *(const uint4v*)(kpl + 8);
        pt  = *(const uint4v*)tpl;
        kpl += 4096; tpl += 64;
        COMPUTE32(Ks0[half], Ts0[half]);
        WGBAR();
        // phase B: compute chunk it+1 (buf1); stage buf0 <- chunk it+2; load it+3
        *(uint4v*)&Ks0[half][Lrow][kpart] = pka;
        *(uint4v*)&Ks0[half][Lrow][kpart + 8] = pkb;
        *(uint4v*)&Ts0[half][srow][scol] = pt;
        pka = *(const uint4v*)kpl;
        pkb = *(const uint4v*)(kpl + 8);
        pt  = *(const uint4v*)tpl;
        kpl += 4096; tpl += 64;
        COMPUTE32(Ks1[half], Ts1[half]);
        WGBAR();
    }

    // ---- epilogue: LDS combine of the two k-halves, then normalize ----
    float* ULDS = (float*)smem;                              // 40960 B
    unsigned char (*TT)[144] = (unsigned char(*)[144])(smem + 40960);  // 9216 B

    if (half == 1) {
        float* ub = ULDS + (size_t)(wsub * 64 + lane) * 40;
#pragma unroll
        for (int j = 0; j < 4; j++) {
            *(float4v*)(ub + j * 4) = acc0[j];
            *(float4v*)(ub + 16 + j * 4) = acc1[j];
        }
        *(float4v*)(ub + 32) = accs0;
        *(float4v*)(ub + 36) = accs1;
    }
    WGBAR();
    if (half == 0) {
        const float* ub = ULDS + (size_t)(wsub * 64 + lane) * 40;
#pragma unroll
        for (int j = 0; j < 4; j++) {
            acc0[j] += *(const float4v*)(ub + j * 4);
            acc1[j] += *(const float4v*)(ub + 16 + j * 4);
        }
        accs0 += *(const float4v*)(ub + 32);
        accs1 += *(const float4v*)(ub + 36);

        int h = bh & 7;
        float ck = coeffs[h * 4 + kidx];
        float rinv0[4], rinv1[4];
#pragma unroll
        for (int reg = 0; reg < 4; reg++) {
            rinv0[reg] = 1.f / accs0[reg];
            rinv1[reg] = 1.f / accs1[reg];
        }
        float tv0[4][4], tv1[4][4];
#pragma unroll
        for (int ni = 0; ni < 4; ni++)
#pragma unroll
            for (int reg = 0; reg < 4; reg++) {
                tv0[ni][reg] = acc0[ni][reg] * rinv0[reg];
                tv1[ni][reg] = acc1[ni][reg] * rinv1[reg];
            }
#pragma unroll
        for (int reg = 0; reg < 4; reg++) {
            int il = wsub * 32 + q * 4 + reg;
            float* yp0 = y + ((size_t)bh * N_ + (size_t)ti * 128 + il) * 64;
            float* yp1 = yp0 + 16 * 64;
#pragma unroll
            for (int ni = 0; ni < 4; ni++) {
                yp0[ni * 16 + r] += ck * tv0[ni][reg];
                yp1[ni * 16 + r] += ck * tv1[ni][reg];
            }
        }
        if (write_t) {
#pragma unroll
            for (int ni = 0; ni < 4; ni++) {
                int p0 = __builtin_amdgcn_cvt_pk_fp8_f32(tv0[ni][0], tv0[ni][1], 0, false);
                p0 = __builtin_amdgcn_cvt_pk_fp8_f32(tv0[ni][2], tv0[ni][3], p0, true);
                *(unsigned int*)&TT[ni * 16 + r][wsub * 32 + q * 4] = (unsigned int)p0;
                int p1 = __builtin_amdgcn_cvt_pk_fp8_f32(tv1[ni][0], tv1[ni][1], 0, false);
                p1 = __builtin_amdgcn_cvt_pk_fp8_f32(tv1[ni][2], tv1[ni][3], p1, true);
                *(unsigned int*)&TT[ni * 16 + r][wsub * 32 + 16 + q * 4] = (unsigned int)p1;
            }
        }
    }
    if (write_t) {
        WGBAR();
        int drow = tid >> 3, dcol = (tid & 7) * 16;   // 64 rows x 128 cols
        uint4v vv = *(const uint4v*)&TT[drow][dcol];
        *(uint4v*)&toutT[(size_t)bh * 64 * N_ + (size_t)drow * N_ + ti * 128 + dcol] = vv;
    }
}

// ---------------- output projection: merged[8192,512] x Wo[512,256] ---------
__global__ __launch_bounds__(256) void out_gemm(
    const float* __restrict__ y, const ushort_t* __restrict__ WoT,
    float* __restrict__ out) {
    __shared__ ushort_t As[128][PAD];
    __shared__ ushort_t Bs[64][PAD];
    int bid = blockIdx.x;
    int tileN = bid & 3, tileM = bid >> 2;
    int tid = threadIdx.x, w = tid >> 6, lane = tid & 63, q = lane >> 4, r = lane & 15;
    int wr = w * 32;
    float4v acc[2][4];
    for (int i = 0; i < 2; i++)
        for (int j = 0; j < 4; j++)
            for (int e = 0; e < 4; e++) acc[i][j][e] = 0.f;

    for (int k0 = 0; k0 < 512; k0 += 64) {
        int h = k0 >> 6;
        for (int it = 0; it < 8; it++) {
            int idx = tid + it * 256;
            int row = idx >> 4, kc = (idx & 15) * 4;
            int grow = tileM * 128 + row;
            int b = grow >> 12, n = grow & 4095;
            const float4* src =
                (const float4*)&y[(((size_t)(b * H_ + h)) * N_ + n) * 64 + kc];
            float4 v = *src;
            ushort4v pv;
            pv[0] = f2bf(v.x); pv[1] = f2bf(v.y); pv[2] = f2bf(v.z); pv[3] = f2bf(v.w);
            *(ushort4v*)&As[row][kc] = pv;
        }
        for (int it = 0; it < 2; it++) {
            int idx = tid + it * 256;
            int row = idx >> 3, kc = (idx & 7) * 8;
            *(short8*)&Bs[row][kc] =
                *(const short8*)&WoT[(size_t)(tileN * 64 + row) * 512 + k0 + kc];
        }
        __syncthreads();
        for (int kk = 0; kk < 64; kk += 32) {
            short8 a[2], b[4];
            a[0] = *(const short8*)&As[wr + r][kk + q * 8];
            a[1] = *(const short8*)&As[wr + 16 + r][kk + q * 8];
            for (int ni = 0; ni < 4; ni++)
                b[ni] = *(const short8*)&Bs[ni * 16 + r][kk + q * 8];
            for (int mi = 0; mi < 2; mi++)
                for (int ni = 0; ni < 4; ni++)
                    acc[mi][ni] = __builtin_amdgcn_mfma_f32_16x16x32_bf16(
                        a[mi], b[ni], acc[mi][ni], 0, 0, 0);
        }
        __syncthreads();
    }
    for (int mi = 0; mi < 2; mi++)
        for (int reg = 0; reg < 4; reg++) {
            int grow = tileM * 128 + wr + mi * 16 + q * 4 + reg;
            for (int ni = 0; ni < 4; ni++) {
                int gcol = tileN * 64 + ni * 16 + r;
                out[(size_t)grow * 256 + gcol] = acc[mi][ni][reg];
            }
        }
}

// ---------------------------------------------------------------------------
extern "C" void kernel_launch(void* const* d_in, const int* in_sizes, int n_in,
                              void* d_out, int out_size, void* d_ws, size_t ws_size,
                              hipStream_t stream) {
    const float* x      = (const float*)d_in[0];
    const float* Wq     = (const float*)d_in[1];
    const float* Wk     = (const float*)d_in[2];
    const float* Wv     = (const float*)d_in[3];
    const float* Wo     = (const float*)d_in[4];
    const float* gamma  = (const float*)d_in[5];
    const float* beta   = (const float*)d_in[6];
    const float* coeffs = (const float*)d_in[7];
    float* out = (float*)d_out;

    char* ws = (char*)d_ws;
    size_t off = 0;
    auto alloc = [&](size_t bytes) -> void* {
        void* p = ws + off;
        off += (bytes + 255) & ~(size_t)255;
        return p;
    };
    ushort_t* xb    = (ushort_t*)alloc((size_t)B_ * N_ * D_ * 2);
    ushort_t* WqkvT = (ushort_t*)alloc((size_t)3 * INNER_ * D_ * 2);
    ushort_t* WoT   = (ushort_t*)alloc((size_t)D_ * INNER_ * 2);
    ushort_t* Qb    = (ushort_t*)alloc((size_t)NBH * N_ * DH_ * 2);
    ushort_t* Kb    = (ushort_t*)alloc((size_t)NBH * N_ * DH_ * 2);
    ushort_t* Vb    = (ushort_t*)alloc((size_t)NBH * N_ * DH_ * 2);
    unsigned char* t0T = (unsigned char*)alloc((size_t)NBH * DH_ * N_);
    unsigned char* t1T = (unsigned char*)alloc((size_t)NBH * DH_ * N_);
    float*    y     = (float*)alloc((size_t)NBH * N_ * DH_ * 4);

    const int prep_total = B_ * N_ * D_ + 3 * INNER_ * D_ + D_ * INNER_;
    prep_kernel<<<(prep_total + 255) / 256, 256, 0, stream>>>(
        x, Wq, Wk, Wv, Wo, xb, WqkvT, WoT);
    proj_gemm<<<768, 256, 0, stream>>>(xb, WqkvT, Qb, Kb, Vb);
    ln_kernel<<<(NBH * N_) / 4, 256, 0, stream>>>(Vb, gamma, beta, coeffs, t0T, y);

    poly_pass<<<NBH * 32, 512, 0, stream>>>(Qb, Kb, t0T, y, t1T, coeffs, 1, 1);
    poly_pass<<<NBH * 32, 512, 0, stream>>>(Qb, Kb, t1T, y, t0T, coeffs, 2, 1);
    poly_pass<<<NBH * 32, 512, 0, stream>>>(Qb, Kb, t0T, y, t1T, coeffs, 3, 0);

    out_gemm<<<256, 256, 0, stream>>>(y, WoT, out);
}